// Round 11
// baseline (367.406 us; speedup 1.0000x reference)
//
#include <hip/hip_runtime.h>
#include <math.h>

// ---------------------------------------------------------------------------
// TopoGAT: 2-layer GAT on MI355X.
// R3/R10: CSR build via two-level binning with FIXED-CAPACITY buckets
//     (C=4608 >= mean 4096 + 8 sigma): no histogram, no scan — k_bin reserves
//     runs off gCursor (init b*C), k_fill2 emits per-node rowptr/rowEnd into
//     a padded CSR. Agg kernels read [rowptr[n], rowEnd[n]).
// R5: gather tables h1/g stored in bf16 (halves random-gather fabric bytes).
// R7: xform kernels as 2D register-tiled GEMM (W+xT in LDS, 4x4 thread tile).
// R8/R9: one wave-wide exp per edge chunk; multi-row gathers (agg1: 2x32
//     lanes = 2 full 128B rows/instr; agg2: 3x20 lanes = 3 x 80B rows/instr).
// R10: 32-bit byte-offset addressing in gather loops; agg1 chunk 8->16 edges.
// ---------------------------------------------------------------------------

#define NBUK_MAX 512
#define BIN_CHUNK 8192
#define BUK_CAP 4608

typedef unsigned short ushort_t;

__device__ inline unsigned int f2bf(float f) {  // RNE fp32->bf16
    unsigned int u = __float_as_uint(f);
    u += 0x7FFFu + ((u >> 16) & 1u);
    return u >> 16;
}
__device__ inline float bf_lo(unsigned int u) {
    return __uint_as_float(u << 16);
}
__device__ inline float bf_hi(unsigned int u) {
    return __uint_as_float(u & 0xFFFF0000u);
}
__device__ inline float lrelu_exp(float q) {
    return __expf(q >= 0.f ? q : 0.2f * q);
}

__device__ inline int wave_incl_scan(int v, int lane) {
    #pragma unroll
    for (int ofs = 1; ofs < 64; ofs <<= 1) {
        int t = __shfl_up(v, ofs);
        if (lane >= ofs) v += t;
    }
    return v;
}

__global__ void k_initcur(int* __restrict__ gCursor, int NBUK) {
    int i = blockIdx.x * blockDim.x + threadIdx.x;
    if (i < NBUK) gCursor[i] = i * BUK_CAP;
}

// Bin edges into fixed-capacity bucket regions of tmp. One global atomic per
// (block,bucket); packed word = (src<<8) | (dst&255).
__global__ __launch_bounds__(256) void k_bin(const int* __restrict__ src,
                                             const int* __restrict__ dst,
                                             int* __restrict__ gCursor,
                                             unsigned int* __restrict__ tmp,
                                             int E, int NBUK) {
    __shared__ int lcnt[NBUK_MAX];
    __shared__ int lcur[NBUK_MAX];
    int tid = threadIdx.x;
    int base = blockIdx.x * BIN_CHUNK;
    for (int i = tid; i < NBUK; i += 256) lcnt[i] = 0;
    __syncthreads();
    #pragma unroll
    for (int k = 0; k < BIN_CHUNK / 256; k++) {
        int i = base + tid + k * 256;
        if (i < E) atomicAdd(&lcnt[dst[i] >> 8], 1);
    }
    __syncthreads();
    for (int b = tid; b < NBUK; b += 256) {
        int c = lcnt[b];
        lcur[b] = c ? atomicAdd(&gCursor[b], c) : 0;
    }
    __syncthreads();
    #pragma unroll
    for (int k = 0; k < BIN_CHUNK / 256; k++) {
        int i = base + tid + k * 256;
        if (i < E) {
            int d = dst[i];
            int p = atomicAdd(&lcur[d >> 8], 1);
            tmp[p] = ((unsigned int)src[i] << 8) | (unsigned int)(d & 255);
        }
    }
}

// Exact CSR fill within a bucket (padded layout, base = b*BUK_CAP).
// Emits rowptr[n] (start) and rowEnd[n]; csr writes confined to block window.
__global__ __launch_bounds__(256) void k_fill2(const unsigned int* __restrict__ tmp,
                                               const int* __restrict__ gCursor,
                                               int* __restrict__ rowptr,
                                               int* __restrict__ rowEnd,
                                               int* __restrict__ csr, int N) {
    __shared__ int cnt[256];
    __shared__ int cur[256];
    __shared__ int wsum[4];
    int b = blockIdx.x, tid = threadIdx.x;
    int lane = tid & 63, wv = tid >> 6;
    int e0 = b * BUK_CAP;
    int e1 = gCursor[b];  // after k_bin: b*BUK_CAP + count_b
    cnt[tid] = 0;
    __syncthreads();
    for (int i = e0 + tid; i < e1; i += 256)
        atomicAdd(&cnt[tmp[i] & 255u], 1);
    __syncthreads();
    int v = cnt[tid];
    int incl = wave_incl_scan(v, lane);
    if (lane == 63) wsum[wv] = incl;
    __syncthreads();
    int woff = 0;
    for (int i = 0; i < wv; i++) woff += wsum[i];
    int excl = woff + incl - v;
    int node = b * 256 + tid;
    int start = e0 + excl;
    if (node < N) { rowptr[node] = start; rowEnd[node] = start + v; }
    cur[tid] = start;
    __syncthreads();
    for (int i = e0 + tid; i < e1; i += 256) {
        unsigned int t = tmp[i];
        int p = atomicAdd(&cur[t & 255u], 1);
        csr[p] = (int)(t >> 8);
    }
}

// h1b[n][64](bf16) = [x[n]|topo[n]] @ W1 ; as1/ad1 from fp32 accumulators.
// Block = 64 nodes x 64 cols GEMM tile, K=136. W1 + xT staged in LDS.
__global__ __launch_bounds__(256) void k_xform1(const float* __restrict__ x,
                                                const float* __restrict__ topo,
                                                const float* __restrict__ W1,
                                                const float* __restrict__ asrc,
                                                const float* __restrict__ adst,
                                                ushort_t* __restrict__ h1b,
                                                float* __restrict__ as1,
                                                float* __restrict__ ad1, int N) {
    __shared__ float XT[136 * 64];  // XT[k][node]
    __shared__ float WS[136 * 64];  // WS[k][col]
    int tid = threadIdx.x;
    int n0 = blockIdx.x * 64;
    {   // stage W1: 8704 floats = 2176 float4 (once per block)
        const float4* W4 = (const float4*)W1;
        float4* WS4 = (float4*)WS;
        for (int i = tid; i < 2176; i += 256) WS4[i] = W4[i];
    }
    {   // stage x transposed: 64 nodes x 32 float4
        const float4* x4 = (const float4*)x;
        for (int i = tid; i < 2048; i += 256) {
            int node = i >> 5, k4 = i & 31;
            int gn = n0 + node; if (gn > N - 1) gn = N - 1;
            float4 v = x4[(size_t)gn * 32 + k4];
            int k = k4 * 4;
            XT[(k + 0) * 64 + node] = v.x;
            XT[(k + 1) * 64 + node] = v.y;
            XT[(k + 2) * 64 + node] = v.z;
            XT[(k + 3) * 64 + node] = v.w;
        }
        // topo rows 128..135: 64 nodes x 2 float4
        const float4* t4 = (const float4*)topo;
        if (tid < 128) {
            int node = tid >> 1, k4 = tid & 1;
            int gn = n0 + node; if (gn > N - 1) gn = N - 1;
            float4 v = t4[(size_t)gn * 2 + k4];
            int k = 128 + k4 * 4;
            XT[(k + 0) * 64 + node] = v.x;
            XT[(k + 1) * 64 + node] = v.y;
            XT[(k + 2) * 64 + node] = v.z;
            XT[(k + 3) * 64 + node] = v.w;
        }
    }
    __syncthreads();
    int ci = tid & 15, ni = tid >> 4;
    int nb = ni * 4, cb = ci * 4;
    float acc[16];
    #pragma unroll
    for (int i = 0; i < 16; i++) acc[i] = 0.f;
    #pragma unroll 4
    for (int k = 0; k < 136; k++) {
        float4 xv = *(const float4*)&XT[k * 64 + nb];
        float4 wv = *(const float4*)&WS[k * 64 + cb];
        acc[0]  = fmaf(xv.x, wv.x, acc[0]);  acc[1]  = fmaf(xv.x, wv.y, acc[1]);
        acc[2]  = fmaf(xv.x, wv.z, acc[2]);  acc[3]  = fmaf(xv.x, wv.w, acc[3]);
        acc[4]  = fmaf(xv.y, wv.x, acc[4]);  acc[5]  = fmaf(xv.y, wv.y, acc[5]);
        acc[6]  = fmaf(xv.y, wv.z, acc[6]);  acc[7]  = fmaf(xv.y, wv.w, acc[7]);
        acc[8]  = fmaf(xv.z, wv.x, acc[8]);  acc[9]  = fmaf(xv.z, wv.y, acc[9]);
        acc[10] = fmaf(xv.z, wv.z, acc[10]); acc[11] = fmaf(xv.z, wv.w, acc[11]);
        acc[12] = fmaf(xv.w, wv.x, acc[12]); acc[13] = fmaf(xv.w, wv.y, acc[13]);
        acc[14] = fmaf(xv.w, wv.z, acc[14]); acc[15] = fmaf(xv.w, wv.w, acc[15]);
    }
    int head = cb >> 3;  // cols cb..cb+3 lie in one head (cb multiple of 4)
    #pragma unroll
    for (int i = 0; i < 4; i++) {
        int n = n0 + nb + i;
        unsigned int p0 = f2bf(acc[i * 4 + 0]) | (f2bf(acc[i * 4 + 1]) << 16);
        unsigned int p1 = f2bf(acc[i * 4 + 2]) | (f2bf(acc[i * 4 + 3]) << 16);
        if (n < N) *(uint2*)&h1b[(size_t)n * 64 + cb] = make_uint2(p0, p1);
        float s = 0.f, d = 0.f;
        #pragma unroll
        for (int j = 0; j < 4; j++) {
            s = fmaf(acc[i * 4 + j], asrc[cb + j], s);
            d = fmaf(acc[i * 4 + j], adst[cb + j], d);
        }
        s += __shfl_xor(s, 1);  // combine the two half-head threads
        d += __shfl_xor(d, 1);
        if ((ci & 1) == 0 && n < N) {
            as1[n * 8 + head] = s;
            ad1[n * 8 + head] = d;
        }
    }
}

// Per-dst softmax-weighted aggregation, layer 1 (+ implicit self loop).
// 2 groups x 32 lanes: lane (g=l>>5, p=l&31) handles cols 2p,2p+1 of every
// 2nd edge -> one uint gather instruction fetches TWO full 128B rows.
// 16-edge chunks, 32-bit byte-offset addressing.
__global__ __launch_bounds__(256) void k_agg1(const ushort_t* __restrict__ h1b,
                                              const float* __restrict__ as1,
                                              const float* __restrict__ ad1,
                                              const float* __restrict__ b1,
                                              const int* __restrict__ rowptr,
                                              const int* __restrict__ rowEnd,
                                              const int* __restrict__ csr,
                                              float* __restrict__ h2, int N) {
    int tid = threadIdx.x, lane = tid & 63;
    int n = blockIdx.x * 4 + (tid >> 6);
    if (n >= N) return;
    int g = lane >> 5, p = lane & 31;
    int c0 = 2 * p;
    int h = p >> 2;  // head of cols c0, c0+1
    const char* h1c = (const char*)h1b;
    const char* as1c = (const char*)as1;
    unsigned coff = (unsigned)(p << 2);   // c0 * 2 bytes
    unsigned hoff = (unsigned)(h << 2);   // head * 4 bytes
    float ad_dl = ad1[n * 8 + h];
    float acc0 = 0.f, acc1 = 0.f, zl = 0.f;
    {   // self loop (group 0 only)
        float e0 = as1[n * 8 + h] + ad_dl;
        float w = lrelu_exp(e0);
        if (g == 0) {
            unsigned int u = *(const unsigned int*)(h1c + (((unsigned)n << 7) + coff));
            acc0 = w * bf_lo(u); acc1 = w * bf_hi(u); zl = w;
        }
    }
    int j0 = rowptr[n], j1 = rowEnd[n];
    int j = j0;
    for (; j + 16 <= j1; j += 16) {
        int cv = csr[j + (lane & 15)];           // coalesced, then bpermute
        int s0 = __shfl(cv, 0 + g), s1 = __shfl(cv, 2 + g);
        int s2 = __shfl(cv, 4 + g), s3 = __shfl(cv, 6 + g);
        int s4 = __shfl(cv, 8 + g), s5 = __shfl(cv, 10 + g);
        int s6 = __shfl(cv, 12 + g), s7 = __shfl(cv, 14 + g);
        unsigned int u0 = *(const unsigned int*)(h1c + (((unsigned)s0 << 7) + coff));
        unsigned int u1 = *(const unsigned int*)(h1c + (((unsigned)s1 << 7) + coff));
        unsigned int u2 = *(const unsigned int*)(h1c + (((unsigned)s2 << 7) + coff));
        unsigned int u3 = *(const unsigned int*)(h1c + (((unsigned)s3 << 7) + coff));
        unsigned int u4 = *(const unsigned int*)(h1c + (((unsigned)s4 << 7) + coff));
        unsigned int u5 = *(const unsigned int*)(h1c + (((unsigned)s5 << 7) + coff));
        unsigned int u6 = *(const unsigned int*)(h1c + (((unsigned)s6 << 7) + coff));
        unsigned int u7 = *(const unsigned int*)(h1c + (((unsigned)s7 << 7) + coff));
        float a0 = *(const float*)(as1c + (((unsigned)s0 << 5) + hoff));
        float a1 = *(const float*)(as1c + (((unsigned)s1 << 5) + hoff));
        float a2 = *(const float*)(as1c + (((unsigned)s2 << 5) + hoff));
        float a3 = *(const float*)(as1c + (((unsigned)s3 << 5) + hoff));
        float a4 = *(const float*)(as1c + (((unsigned)s4 << 5) + hoff));
        float a5 = *(const float*)(as1c + (((unsigned)s5 << 5) + hoff));
        float a6 = *(const float*)(as1c + (((unsigned)s6 << 5) + hoff));
        float a7 = *(const float*)(as1c + (((unsigned)s7 << 5) + hoff));
        float w0 = lrelu_exp(a0 + ad_dl);
        float w1 = lrelu_exp(a1 + ad_dl);
        float w2 = lrelu_exp(a2 + ad_dl);
        float w3 = lrelu_exp(a3 + ad_dl);
        float w4 = lrelu_exp(a4 + ad_dl);
        float w5 = lrelu_exp(a5 + ad_dl);
        float w6 = lrelu_exp(a6 + ad_dl);
        float w7 = lrelu_exp(a7 + ad_dl);
        acc0 = fmaf(w0, bf_lo(u0), acc0); acc1 = fmaf(w0, bf_hi(u0), acc1); zl += w0;
        acc0 = fmaf(w1, bf_lo(u1), acc0); acc1 = fmaf(w1, bf_hi(u1), acc1); zl += w1;
        acc0 = fmaf(w2, bf_lo(u2), acc0); acc1 = fmaf(w2, bf_hi(u2), acc1); zl += w2;
        acc0 = fmaf(w3, bf_lo(u3), acc0); acc1 = fmaf(w3, bf_hi(u3), acc1); zl += w3;
        acc0 = fmaf(w4, bf_lo(u4), acc0); acc1 = fmaf(w4, bf_hi(u4), acc1); zl += w4;
        acc0 = fmaf(w5, bf_lo(u5), acc0); acc1 = fmaf(w5, bf_hi(u5), acc1); zl += w5;
        acc0 = fmaf(w6, bf_lo(u6), acc0); acc1 = fmaf(w6, bf_hi(u6), acc1); zl += w6;
        acc0 = fmaf(w7, bf_lo(u7), acc0); acc1 = fmaf(w7, bf_hi(u7), acc1); zl += w7;
    }
    for (; j + 2 <= j1; j += 2) {
        int s = csr[j + g];
        float a = *(const float*)(as1c + (((unsigned)s << 5) + hoff));
        unsigned int u = *(const unsigned int*)(h1c + (((unsigned)s << 7) + coff));
        float w = lrelu_exp(a + ad_dl);
        acc0 = fmaf(w, bf_lo(u), acc0); acc1 = fmaf(w, bf_hi(u), acc1); zl += w;
    }
    for (; j < j1; ++j) {  // last odd edge: group 0 only
        int s = csr[j];
        float a = *(const float*)(as1c + (((unsigned)s << 5) + hoff));
        unsigned int u = *(const unsigned int*)(h1c + (((unsigned)s << 7) + coff));
        float w = (g == 0) ? lrelu_exp(a + ad_dl) : 0.f;
        acc0 = fmaf(w, bf_lo(u), acc0); acc1 = fmaf(w, bf_hi(u), acc1); zl += w;
    }
    float A0 = acc0 + __shfl_xor(acc0, 32);
    float A1 = acc1 + __shfl_xor(acc1, 32);
    float Z  = zl + __shfl_xor(zl, 32);
    if (g == 0) {
        float inv = 1.f / (Z + 1e-16f);
        float v0 = A0 * inv + b1[c0];
        float v1 = A1 * inv + b1[c0 + 1];
        v0 = v0 > 0.f ? v0 : (__expf(v0) - 1.f);
        v1 = v1 > 0.f ? v1 : (__expf(v1) - 1.f);
        *(float2*)&h2[(size_t)n * 64 + c0] = make_float2(v0, v1);
    }
}

// gb[n][40](bf16) = h2[n] @ W2 ; as2/ad2 from fp32 accumulators.
// Block = 64 nodes x 40 cols GEMM tile, K=64.
__global__ __launch_bounds__(256) void k_xform2(const float* __restrict__ h2,
                                                const float* __restrict__ W2,
                                                const float* __restrict__ asrc2,
                                                const float* __restrict__ adst2,
                                                ushort_t* __restrict__ gb,
                                                float* __restrict__ as2,
                                                float* __restrict__ ad2, int N) {
    __shared__ float XT[64 * 64];  // h2T[k][node]
    __shared__ float WS[64 * 40];  // WS[k][col]
    int tid = threadIdx.x;
    int n0 = blockIdx.x * 64;
    {   // stage W2: 2560 floats = 640 float4
        const float4* W4 = (const float4*)W2;
        float4* WS4 = (float4*)WS;
        for (int i = tid; i < 640; i += 256) WS4[i] = W4[i];
    }
    {   // stage h2 transposed: 64 nodes x 16 float4
        const float4* h4 = (const float4*)h2;
        for (int i = tid; i < 1024; i += 256) {
            int node = i >> 4, k4 = i & 15;
            int gn = n0 + node; if (gn > N - 1) gn = N - 1;
            float4 v = h4[(size_t)gn * 16 + k4];
            int k = k4 * 4;
            XT[(k + 0) * 64 + node] = v.x;
            XT[(k + 1) * 64 + node] = v.y;
            XT[(k + 2) * 64 + node] = v.z;
            XT[(k + 3) * 64 + node] = v.w;
        }
    }
    __syncthreads();
    int ci = tid & 15, ni = tid >> 4;
    int nb = ni * 4, cb = ci * 4;
    float acc[16];
    #pragma unroll
    for (int i = 0; i < 16; i++) acc[i] = 0.f;
    if (ci < 10) {
        #pragma unroll 4
        for (int k = 0; k < 64; k++) {
            float4 xv = *(const float4*)&XT[k * 64 + nb];
            float4 wv = *(const float4*)&WS[k * 40 + cb];
            acc[0]  = fmaf(xv.x, wv.x, acc[0]);  acc[1]  = fmaf(xv.x, wv.y, acc[1]);
            acc[2]  = fmaf(xv.x, wv.z, acc[2]);  acc[3]  = fmaf(xv.x, wv.w, acc[3]);
            acc[4]  = fmaf(xv.y, wv.x, acc[4]);  acc[5]  = fmaf(xv.y, wv.y, acc[5]);
            acc[6]  = fmaf(xv.y, wv.z, acc[6]);  acc[7]  = fmaf(xv.y, wv.w, acc[7]);
            acc[8]  = fmaf(xv.z, wv.x, acc[8]);  acc[9]  = fmaf(xv.z, wv.y, acc[9]);
            acc[10] = fmaf(xv.z, wv.z, acc[10]); acc[11] = fmaf(xv.z, wv.w, acc[11]);
            acc[12] = fmaf(xv.w, wv.x, acc[12]); acc[13] = fmaf(xv.w, wv.y, acc[13]);
            acc[14] = fmaf(xv.w, wv.z, acc[14]); acc[15] = fmaf(xv.w, wv.w, acc[15]);
        }
    }
    #pragma unroll
    for (int i = 0; i < 4; i++) {
        int n = n0 + nb + i;
        if (ci < 10 && n < N) {
            unsigned int p0 = f2bf(acc[i * 4 + 0]) | (f2bf(acc[i * 4 + 1]) << 16);
            unsigned int p1 = f2bf(acc[i * 4 + 2]) | (f2bf(acc[i * 4 + 3]) << 16);
            *(uint2*)&gb[(size_t)n * 40 + cb] = make_uint2(p0, p1);
        }
        float s = 0.f, d = 0.f;
        if (ci < 10) {
            #pragma unroll
            for (int j = 0; j < 4; j++) {
                s = fmaf(acc[i * 4 + j], asrc2[cb + j], s);
                d = fmaf(acc[i * 4 + j], adst2[cb + j], d);
            }
        }
        // reduce over the 16-lane ci group (ci>=10 contribute 0)
        s += __shfl_xor(s, 1); s += __shfl_xor(s, 2);
        s += __shfl_xor(s, 4); s += __shfl_xor(s, 8);
        d += __shfl_xor(d, 1); d += __shfl_xor(d, 2);
        d += __shfl_xor(d, 4); d += __shfl_xor(d, 8);
        if (ci == 0 && n < N) { as2[n] = s; ad2[n] = d; }
    }
}

// Layer-2 aggregation + bias + log_softmax.
// 3 groups x 20 lanes: one uint gather instruction fetches THREE 80B rows.
__global__ __launch_bounds__(256) void k_agg2(const ushort_t* __restrict__ gb,
                                              const float* __restrict__ as2,
                                              const float* __restrict__ ad2,
                                              const float* __restrict__ b2,
                                              const int* __restrict__ rowptr,
                                              const int* __restrict__ rowEnd,
                                              const int* __restrict__ csr,
                                              float* __restrict__ out, int N) {
    int tid = threadIdx.x, lane = tid & 63;
    int n = blockIdx.x * 4 + (tid >> 6);
    if (n >= N) return;
    int g = lane / 20, p = lane % 20;  // g==3 for lanes 60-63 (results unread)
    int c0 = 2 * p;
    const char* gbc = (const char*)gb;
    unsigned coff = (unsigned)(p << 2);
    float add = ad2[n];
    float acc0 = 0.f, acc1 = 0.f, zl = 0.f;
    {   // self loop (group 0 only)
        float e0 = as2[n] + add;
        float w = lrelu_exp(e0);
        if (g == 0) {
            unsigned int u = *(const unsigned int*)(gbc + ((unsigned)n * 80u + coff));
            acc0 = w * bf_lo(u); acc1 = w * bf_hi(u); zl = w;
        }
    }
    int j0 = rowptr[n], j1 = rowEnd[n];
    int j = j0;
    int gi0 = (0 + g) < 12 ? (0 + g) : 11;   // clamp for g==3 lanes
    int gi1 = (3 + g) < 12 ? (3 + g) : 11;
    int gi2 = (6 + g) < 12 ? (6 + g) : 11;
    int gi3 = (9 + g) < 12 ? (9 + g) : 11;
    for (; j + 12 <= j1; j += 12) {
        int cv = csr[j + (lane % 12)];   // coalesced, then bpermute
        int s0 = __shfl(cv, gi0);
        int s1 = __shfl(cv, gi1);
        int s2 = __shfl(cv, gi2);
        int s3 = __shfl(cv, gi3);
        float a0 = as2[s0], a1 = as2[s1], a2 = as2[s2], a3 = as2[s3];
        unsigned int u0 = *(const unsigned int*)(gbc + ((unsigned)s0 * 80u + coff));
        unsigned int u1 = *(const unsigned int*)(gbc + ((unsigned)s1 * 80u + coff));
        unsigned int u2 = *(const unsigned int*)(gbc + ((unsigned)s2 * 80u + coff));
        unsigned int u3 = *(const unsigned int*)(gbc + ((unsigned)s3 * 80u + coff));
        float w0 = lrelu_exp(a0 + add);
        float w1 = lrelu_exp(a1 + add);
        float w2 = lrelu_exp(a2 + add);
        float w3 = lrelu_exp(a3 + add);
        acc0 = fmaf(w0, bf_lo(u0), acc0); acc1 = fmaf(w0, bf_hi(u0), acc1); zl += w0;
        acc0 = fmaf(w1, bf_lo(u1), acc0); acc1 = fmaf(w1, bf_hi(u1), acc1); zl += w1;
        acc0 = fmaf(w2, bf_lo(u2), acc0); acc1 = fmaf(w2, bf_hi(u2), acc1); zl += w2;
        acc0 = fmaf(w3, bf_lo(u3), acc0); acc1 = fmaf(w3, bf_hi(u3), acc1); zl += w3;
    }
    for (; j + 3 <= j1; j += 3) {
        int s = csr[j + (g < 3 ? g : 2)];
        float a = as2[s];
        unsigned int u = *(const unsigned int*)(gbc + ((unsigned)s * 80u + coff));
        float w = lrelu_exp(a + add);
        acc0 = fmaf(w, bf_lo(u), acc0); acc1 = fmaf(w, bf_hi(u), acc1); zl += w;
    }
    for (; j < j1; ++j) {  // remaining 1-2 edges: group 0 only
        int s = csr[j];
        float a = as2[s];
        unsigned int u = *(const unsigned int*)(gbc + ((unsigned)s * 80u + coff));
        float w = (g == 0) ? lrelu_exp(a + add) : 0.f;
        acc0 = fmaf(w, bf_lo(u), acc0); acc1 = fmaf(w, bf_hi(u), acc1); zl += w;
    }
    // combine the 3 groups (valid at lanes 0..19)
    float A0 = acc0 + __shfl(acc0, (lane + 20) & 63) + __shfl(acc0, (lane + 40) & 63);
    float A1 = acc1 + __shfl(acc1, (lane + 20) & 63) + __shfl(acc1, (lane + 40) & 63);
    float Z  = zl + __shfl(zl, (lane + 20) & 63) + __shfl(zl, (lane + 40) & 63);
    float l0 = 0.f, l1 = 0.f;
    bool active = (lane < 20);
    if (active) {
        float inv = 1.f / (Z + 1e-16f);
        l0 = A0 * inv + b2[c0];
        l1 = A1 * inv + b2[c0 + 1];
    }
    // masked 32-lane butterfly for max and sum-exp over the 40 logits
    float mv = active ? fmaxf(l0, l1) : -INFINITY;
    #pragma unroll
    for (int ofs = 1; ofs < 32; ofs <<= 1) mv = fmaxf(mv, __shfl_xor(mv, ofs));
    float ev = active ? (__expf(l0 - mv) + __expf(l1 - mv)) : 0.f;
    #pragma unroll
    for (int ofs = 1; ofs < 32; ofs <<= 1) ev += __shfl_xor(ev, ofs);
    if (active) {
        float ls = mv + __logf(ev);
        *(float2*)&out[(size_t)n * 40 + c0] = make_float2(l0 - ls, l1 - ls);
    }
}

extern "C" void kernel_launch(void* const* d_in, const int* in_sizes, int n_in,
                              void* d_out, int out_size, void* d_ws, size_t ws_size,
                              hipStream_t stream) {
    const float* x    = (const float*)d_in[0];
    const float* topo = (const float*)d_in[1];
    const int*   ei   = (const int*)d_in[2];
    const float* W1   = (const float*)d_in[3];
    const float* a_s1 = (const float*)d_in[4];
    const float* a_d1 = (const float*)d_in[5];
    const float* b1   = (const float*)d_in[6];
    const float* W2   = (const float*)d_in[7];
    const float* a_s2 = (const float*)d_in[8];
    const float* a_d2 = (const float*)d_in[9];
    const float* b2   = (const float*)d_in[10];
    float* out = (float*)d_out;

    int N = in_sizes[0] / 128;
    int E = in_sizes[2] / 2;
    const int* esrc = ei;
    const int* edst = ei + E;
    int NBUK = (N + 255) / 256;
    size_t cap = (size_t)NBUK * BUK_CAP;

    char* ws = (char*)d_ws;
    size_t off = 0;
    auto alloc = [&](size_t bytes) -> void* {
        void* p = ws + off;
        off = (off + bytes + 255) & ~(size_t)255;
        return p;
    };
    ushort_t* h1b  = (ushort_t*)alloc((size_t)N * 64 * 2);
    float* as1     = (float*)alloc((size_t)N * 8 * 4);
    float* ad1     = (float*)alloc((size_t)N * 8 * 4);
    float* h2      = (float*)alloc((size_t)N * 64 * 4);
    ushort_t* gb   = (ushort_t*)alloc((size_t)N * 40 * 2);
    float* as2     = (float*)alloc((size_t)N * 4);
    float* ad2     = (float*)alloc((size_t)N * 4);
    int*   rowptr  = (int*)alloc((size_t)N * 4);
    int*   rowEnd  = (int*)alloc((size_t)N * 4);
    int*   csr     = (int*)alloc(cap * 4);
    unsigned int* tmp = (unsigned int*)alloc(cap * 4);
    int* gCursor   = (int*)alloc((size_t)NBUK * 4);

    k_initcur<<<(NBUK + 255) / 256, 256, 0, stream>>>(gCursor, NBUK);
    int nbin = (E + BIN_CHUNK - 1) / BIN_CHUNK;
    k_bin<<<nbin, 256, 0, stream>>>(esrc, edst, gCursor, tmp, E, NBUK);
    k_fill2<<<NBUK, 256, 0, stream>>>(tmp, gCursor, rowptr, rowEnd, csr, N);

    int nbg = (N + 63) / 64;  // 64-node GEMM tiles
    int nb4 = (N + 3) / 4;    // 1 node/wave x 4 waves/block
    k_xform1<<<nbg, 256, 0, stream>>>(x, topo, W1, a_s1, a_d1, h1b, as1, ad1, N);
    k_agg1<<<nb4, 256, 0, stream>>>(h1b, as1, ad1, b1, rowptr, rowEnd, csr, h2, N);
    k_xform2<<<nbg, 256, 0, stream>>>(h2, W2, a_s2, a_d2, gb, as2, ad2, N);
    k_agg2<<<nb4, 256, 0, stream>>>(gb, as2, ad2, b2, rowptr, rowEnd, csr, out, N);
}

// Round 12
// 354.522 us; speedup vs baseline: 1.0363x; 1.0363x over previous
//
#include <hip/hip_runtime.h>
#include <math.h>

// ---------------------------------------------------------------------------
// TopoGAT: 2-layer GAT on MI355X.
// R10: fixed-capacity bucket CSR build (no histogram/scan); padded CSR with
//      per-node rowptr/rowEnd.
// R5:  gather tables h1/g in bf16. R7: xform = LDS-tiled GEMM. R8/R9: one
//      wave-wide exp per chunk; multi-row gathers (agg1 2x32 lanes -> 2 full
//      128B rows/instr; agg2 3x20 -> 3 x 80B rows/instr).
// R11: agg1 chunk reverted 16->8 edges (Poisson(16) degrees: 16-chunk pushed
//      half the edges into the serial 2-edge tail) and BOTH agg tails are now
//      ONE masked full-width iteration (clamped csr index, zeroed weights) —
//      no serial dependent-gather remainder at all.
// ---------------------------------------------------------------------------

#define NBUK_MAX 512
#define BIN_CHUNK 8192
#define BUK_CAP 4608

typedef unsigned short ushort_t;

__device__ inline unsigned int f2bf(float f) {  // RNE fp32->bf16
    unsigned int u = __float_as_uint(f);
    u += 0x7FFFu + ((u >> 16) & 1u);
    return u >> 16;
}
__device__ inline float bf_lo(unsigned int u) {
    return __uint_as_float(u << 16);
}
__device__ inline float bf_hi(unsigned int u) {
    return __uint_as_float(u & 0xFFFF0000u);
}
__device__ inline float lrelu_exp(float q) {
    return __expf(q >= 0.f ? q : 0.2f * q);
}

__device__ inline int wave_incl_scan(int v, int lane) {
    #pragma unroll
    for (int ofs = 1; ofs < 64; ofs <<= 1) {
        int t = __shfl_up(v, ofs);
        if (lane >= ofs) v += t;
    }
    return v;
}

__global__ void k_initcur(int* __restrict__ gCursor, int NBUK) {
    int i = blockIdx.x * blockDim.x + threadIdx.x;
    if (i < NBUK) gCursor[i] = i * BUK_CAP;
}

// Bin edges into fixed-capacity bucket regions of tmp. One global atomic per
// (block,bucket); packed word = (src<<8) | (dst&255).
__global__ __launch_bounds__(256) void k_bin(const int* __restrict__ src,
                                             const int* __restrict__ dst,
                                             int* __restrict__ gCursor,
                                             unsigned int* __restrict__ tmp,
                                             int E, int NBUK) {
    __shared__ int lcnt[NBUK_MAX];
    __shared__ int lcur[NBUK_MAX];
    int tid = threadIdx.x;
    int base = blockIdx.x * BIN_CHUNK;
    for (int i = tid; i < NBUK; i += 256) lcnt[i] = 0;
    __syncthreads();
    #pragma unroll
    for (int k = 0; k < BIN_CHUNK / 256; k++) {
        int i = base + tid + k * 256;
        if (i < E) atomicAdd(&lcnt[dst[i] >> 8], 1);
    }
    __syncthreads();
    for (int b = tid; b < NBUK; b += 256) {
        int c = lcnt[b];
        lcur[b] = c ? atomicAdd(&gCursor[b], c) : 0;
    }
    __syncthreads();
    #pragma unroll
    for (int k = 0; k < BIN_CHUNK / 256; k++) {
        int i = base + tid + k * 256;
        if (i < E) {
            int d = dst[i];
            int p = atomicAdd(&lcur[d >> 8], 1);
            tmp[p] = ((unsigned int)src[i] << 8) | (unsigned int)(d & 255);
        }
    }
}

// Exact CSR fill within a bucket (padded layout, base = b*BUK_CAP).
// Emits rowptr[n] (start) and rowEnd[n]; csr writes confined to block window.
__global__ __launch_bounds__(256) void k_fill2(const unsigned int* __restrict__ tmp,
                                               const int* __restrict__ gCursor,
                                               int* __restrict__ rowptr,
                                               int* __restrict__ rowEnd,
                                               int* __restrict__ csr, int N) {
    __shared__ int cnt[256];
    __shared__ int cur[256];
    __shared__ int wsum[4];
    int b = blockIdx.x, tid = threadIdx.x;
    int lane = tid & 63, wv = tid >> 6;
    int e0 = b * BUK_CAP;
    int e1 = gCursor[b];  // after k_bin: b*BUK_CAP + count_b
    cnt[tid] = 0;
    __syncthreads();
    for (int i = e0 + tid; i < e1; i += 256)
        atomicAdd(&cnt[tmp[i] & 255u], 1);
    __syncthreads();
    int v = cnt[tid];
    int incl = wave_incl_scan(v, lane);
    if (lane == 63) wsum[wv] = incl;
    __syncthreads();
    int woff = 0;
    for (int i = 0; i < wv; i++) woff += wsum[i];
    int excl = woff + incl - v;
    int node = b * 256 + tid;
    int start = e0 + excl;
    if (node < N) { rowptr[node] = start; rowEnd[node] = start + v; }
    cur[tid] = start;
    __syncthreads();
    for (int i = e0 + tid; i < e1; i += 256) {
        unsigned int t = tmp[i];
        int p = atomicAdd(&cur[t & 255u], 1);
        csr[p] = (int)(t >> 8);
    }
}

// h1b[n][64](bf16) = [x[n]|topo[n]] @ W1 ; as1/ad1 from fp32 accumulators.
// Block = 64 nodes x 64 cols GEMM tile, K=136. W1 + xT staged in LDS.
__global__ __launch_bounds__(256) void k_xform1(const float* __restrict__ x,
                                                const float* __restrict__ topo,
                                                const float* __restrict__ W1,
                                                const float* __restrict__ asrc,
                                                const float* __restrict__ adst,
                                                ushort_t* __restrict__ h1b,
                                                float* __restrict__ as1,
                                                float* __restrict__ ad1, int N) {
    __shared__ float XT[136 * 64];  // XT[k][node]
    __shared__ float WS[136 * 64];  // WS[k][col]
    int tid = threadIdx.x;
    int n0 = blockIdx.x * 64;
    {   // stage W1: 8704 floats = 2176 float4 (once per block)
        const float4* W4 = (const float4*)W1;
        float4* WS4 = (float4*)WS;
        for (int i = tid; i < 2176; i += 256) WS4[i] = W4[i];
    }
    {   // stage x transposed: 64 nodes x 32 float4
        const float4* x4 = (const float4*)x;
        for (int i = tid; i < 2048; i += 256) {
            int node = i >> 5, k4 = i & 31;
            int gn = n0 + node; if (gn > N - 1) gn = N - 1;
            float4 v = x4[(size_t)gn * 32 + k4];
            int k = k4 * 4;
            XT[(k + 0) * 64 + node] = v.x;
            XT[(k + 1) * 64 + node] = v.y;
            XT[(k + 2) * 64 + node] = v.z;
            XT[(k + 3) * 64 + node] = v.w;
        }
        // topo rows 128..135: 64 nodes x 2 float4
        const float4* t4 = (const float4*)topo;
        if (tid < 128) {
            int node = tid >> 1, k4 = tid & 1;
            int gn = n0 + node; if (gn > N - 1) gn = N - 1;
            float4 v = t4[(size_t)gn * 2 + k4];
            int k = 128 + k4 * 4;
            XT[(k + 0) * 64 + node] = v.x;
            XT[(k + 1) * 64 + node] = v.y;
            XT[(k + 2) * 64 + node] = v.z;
            XT[(k + 3) * 64 + node] = v.w;
        }
    }
    __syncthreads();
    int ci = tid & 15, ni = tid >> 4;
    int nb = ni * 4, cb = ci * 4;
    float acc[16];
    #pragma unroll
    for (int i = 0; i < 16; i++) acc[i] = 0.f;
    #pragma unroll 4
    for (int k = 0; k < 136; k++) {
        float4 xv = *(const float4*)&XT[k * 64 + nb];
        float4 wv = *(const float4*)&WS[k * 64 + cb];
        acc[0]  = fmaf(xv.x, wv.x, acc[0]);  acc[1]  = fmaf(xv.x, wv.y, acc[1]);
        acc[2]  = fmaf(xv.x, wv.z, acc[2]);  acc[3]  = fmaf(xv.x, wv.w, acc[3]);
        acc[4]  = fmaf(xv.y, wv.x, acc[4]);  acc[5]  = fmaf(xv.y, wv.y, acc[5]);
        acc[6]  = fmaf(xv.y, wv.z, acc[6]);  acc[7]  = fmaf(xv.y, wv.w, acc[7]);
        acc[8]  = fmaf(xv.z, wv.x, acc[8]);  acc[9]  = fmaf(xv.z, wv.y, acc[9]);
        acc[10] = fmaf(xv.z, wv.z, acc[10]); acc[11] = fmaf(xv.z, wv.w, acc[11]);
        acc[12] = fmaf(xv.w, wv.x, acc[12]); acc[13] = fmaf(xv.w, wv.y, acc[13]);
        acc[14] = fmaf(xv.w, wv.z, acc[14]); acc[15] = fmaf(xv.w, wv.w, acc[15]);
    }
    int head = cb >> 3;  // cols cb..cb+3 lie in one head (cb multiple of 4)
    #pragma unroll
    for (int i = 0; i < 4; i++) {
        int n = n0 + nb + i;
        unsigned int p0 = f2bf(acc[i * 4 + 0]) | (f2bf(acc[i * 4 + 1]) << 16);
        unsigned int p1 = f2bf(acc[i * 4 + 2]) | (f2bf(acc[i * 4 + 3]) << 16);
        if (n < N) *(uint2*)&h1b[(size_t)n * 64 + cb] = make_uint2(p0, p1);
        float s = 0.f, d = 0.f;
        #pragma unroll
        for (int j = 0; j < 4; j++) {
            s = fmaf(acc[i * 4 + j], asrc[cb + j], s);
            d = fmaf(acc[i * 4 + j], adst[cb + j], d);
        }
        s += __shfl_xor(s, 1);  // combine the two half-head threads
        d += __shfl_xor(d, 1);
        if ((ci & 1) == 0 && n < N) {
            as1[n * 8 + head] = s;
            ad1[n * 8 + head] = d;
        }
    }
}

// Per-dst softmax-weighted aggregation, layer 1 (+ implicit self loop).
// 2 groups x 32 lanes: one uint gather instruction fetches TWO full 128B
// rows. 8-edge chunks + ONE masked 8-wide tail iteration.
__global__ __launch_bounds__(256) void k_agg1(const ushort_t* __restrict__ h1b,
                                              const float* __restrict__ as1,
                                              const float* __restrict__ ad1,
                                              const float* __restrict__ b1,
                                              const int* __restrict__ rowptr,
                                              const int* __restrict__ rowEnd,
                                              const int* __restrict__ csr,
                                              float* __restrict__ h2, int N) {
    int tid = threadIdx.x, lane = tid & 63;
    int n = blockIdx.x * 4 + (tid >> 6);
    if (n >= N) return;
    int g = lane >> 5, p = lane & 31;
    int c0 = 2 * p;
    int h = p >> 2;  // head of cols c0, c0+1
    const char* h1c = (const char*)h1b;
    const char* as1c = (const char*)as1;
    unsigned coff = (unsigned)(p << 2);   // c0 * 2 bytes
    unsigned hoff = (unsigned)(h << 2);   // head * 4 bytes
    float ad_dl = ad1[n * 8 + h];
    float acc0 = 0.f, acc1 = 0.f, zl = 0.f;
    {   // self loop (group 0 only)
        float e0 = as1[n * 8 + h] + ad_dl;
        float w = lrelu_exp(e0);
        if (g == 0) {
            unsigned int u = *(const unsigned int*)(h1c + (((unsigned)n << 7) + coff));
            acc0 = w * bf_lo(u); acc1 = w * bf_hi(u); zl = w;
        }
    }
    int j0 = rowptr[n], j1 = rowEnd[n];
    int j = j0;
    for (; j + 8 <= j1; j += 8) {
        int cv = csr[j + (lane & 7)];           // coalesced, then bpermute
        int s0 = __shfl(cv, 0 + g);
        int s1 = __shfl(cv, 2 + g);
        int s2 = __shfl(cv, 4 + g);
        int s3 = __shfl(cv, 6 + g);
        unsigned int u0 = *(const unsigned int*)(h1c + (((unsigned)s0 << 7) + coff));
        unsigned int u1 = *(const unsigned int*)(h1c + (((unsigned)s1 << 7) + coff));
        unsigned int u2 = *(const unsigned int*)(h1c + (((unsigned)s2 << 7) + coff));
        unsigned int u3 = *(const unsigned int*)(h1c + (((unsigned)s3 << 7) + coff));
        float a0 = *(const float*)(as1c + (((unsigned)s0 << 5) + hoff));
        float a1 = *(const float*)(as1c + (((unsigned)s1 << 5) + hoff));
        float a2 = *(const float*)(as1c + (((unsigned)s2 << 5) + hoff));
        float a3 = *(const float*)(as1c + (((unsigned)s3 << 5) + hoff));
        float w0 = lrelu_exp(a0 + ad_dl);
        float w1 = lrelu_exp(a1 + ad_dl);
        float w2 = lrelu_exp(a2 + ad_dl);
        float w3 = lrelu_exp(a3 + ad_dl);
        acc0 = fmaf(w0, bf_lo(u0), acc0); acc1 = fmaf(w0, bf_hi(u0), acc1); zl += w0;
        acc0 = fmaf(w1, bf_lo(u1), acc0); acc1 = fmaf(w1, bf_hi(u1), acc1); zl += w1;
        acc0 = fmaf(w2, bf_lo(u2), acc0); acc1 = fmaf(w2, bf_hi(u2), acc1); zl += w2;
        acc0 = fmaf(w3, bf_lo(u3), acc0); acc1 = fmaf(w3, bf_hi(u3), acc1); zl += w3;
    }
    int t = j1 - j;
    if (t > 0) {  // masked 8-wide tail: clamped index, zeroed weights
        int idx = lane & 7; idx = idx < t ? idx : t - 1;
        int cv = csr[j + idx];
        #pragma unroll
        for (int i = 0; i < 4; i++) {
            int e = 2 * i + g;
            int s = __shfl(cv, e);  // lane e holds csr[j+min(e,t-1)]
            unsigned int u = *(const unsigned int*)(h1c + (((unsigned)s << 7) + coff));
            float a = *(const float*)(as1c + (((unsigned)s << 5) + hoff));
            float w = (e < t) ? lrelu_exp(a + ad_dl) : 0.f;
            acc0 = fmaf(w, bf_lo(u), acc0); acc1 = fmaf(w, bf_hi(u), acc1); zl += w;
        }
    }
    float A0 = acc0 + __shfl_xor(acc0, 32);
    float A1 = acc1 + __shfl_xor(acc1, 32);
    float Z  = zl + __shfl_xor(zl, 32);
    if (g == 0) {
        float inv = 1.f / (Z + 1e-16f);
        float v0 = A0 * inv + b1[c0];
        float v1 = A1 * inv + b1[c0 + 1];
        v0 = v0 > 0.f ? v0 : (__expf(v0) - 1.f);
        v1 = v1 > 0.f ? v1 : (__expf(v1) - 1.f);
        *(float2*)&h2[(size_t)n * 64 + c0] = make_float2(v0, v1);
    }
}

// gb[n][40](bf16) = h2[n] @ W2 ; as2/ad2 from fp32 accumulators.
// Block = 64 nodes x 40 cols GEMM tile, K=64.
__global__ __launch_bounds__(256) void k_xform2(const float* __restrict__ h2,
                                                const float* __restrict__ W2,
                                                const float* __restrict__ asrc2,
                                                const float* __restrict__ adst2,
                                                ushort_t* __restrict__ gb,
                                                float* __restrict__ as2,
                                                float* __restrict__ ad2, int N) {
    __shared__ float XT[64 * 64];  // h2T[k][node]
    __shared__ float WS[64 * 40];  // WS[k][col]
    int tid = threadIdx.x;
    int n0 = blockIdx.x * 64;
    {   // stage W2: 2560 floats = 640 float4
        const float4* W4 = (const float4*)W2;
        float4* WS4 = (float4*)WS;
        for (int i = tid; i < 640; i += 256) WS4[i] = W4[i];
    }
    {   // stage h2 transposed: 64 nodes x 16 float4
        const float4* h4 = (const float4*)h2;
        for (int i = tid; i < 1024; i += 256) {
            int node = i >> 4, k4 = i & 15;
            int gn = n0 + node; if (gn > N - 1) gn = N - 1;
            float4 v = h4[(size_t)gn * 16 + k4];
            int k = k4 * 4;
            XT[(k + 0) * 64 + node] = v.x;
            XT[(k + 1) * 64 + node] = v.y;
            XT[(k + 2) * 64 + node] = v.z;
            XT[(k + 3) * 64 + node] = v.w;
        }
    }
    __syncthreads();
    int ci = tid & 15, ni = tid >> 4;
    int nb = ni * 4, cb = ci * 4;
    float acc[16];
    #pragma unroll
    for (int i = 0; i < 16; i++) acc[i] = 0.f;
    if (ci < 10) {
        #pragma unroll 4
        for (int k = 0; k < 64; k++) {
            float4 xv = *(const float4*)&XT[k * 64 + nb];
            float4 wv = *(const float4*)&WS[k * 40 + cb];
            acc[0]  = fmaf(xv.x, wv.x, acc[0]);  acc[1]  = fmaf(xv.x, wv.y, acc[1]);
            acc[2]  = fmaf(xv.x, wv.z, acc[2]);  acc[3]  = fmaf(xv.x, wv.w, acc[3]);
            acc[4]  = fmaf(xv.y, wv.x, acc[4]);  acc[5]  = fmaf(xv.y, wv.y, acc[5]);
            acc[6]  = fmaf(xv.y, wv.z, acc[6]);  acc[7]  = fmaf(xv.y, wv.w, acc[7]);
            acc[8]  = fmaf(xv.z, wv.x, acc[8]);  acc[9]  = fmaf(xv.z, wv.y, acc[9]);
            acc[10] = fmaf(xv.z, wv.z, acc[10]); acc[11] = fmaf(xv.z, wv.w, acc[11]);
            acc[12] = fmaf(xv.w, wv.x, acc[12]); acc[13] = fmaf(xv.w, wv.y, acc[13]);
            acc[14] = fmaf(xv.w, wv.z, acc[14]); acc[15] = fmaf(xv.w, wv.w, acc[15]);
        }
    }
    #pragma unroll
    for (int i = 0; i < 4; i++) {
        int n = n0 + nb + i;
        if (ci < 10 && n < N) {
            unsigned int p0 = f2bf(acc[i * 4 + 0]) | (f2bf(acc[i * 4 + 1]) << 16);
            unsigned int p1 = f2bf(acc[i * 4 + 2]) | (f2bf(acc[i * 4 + 3]) << 16);
            *(uint2*)&gb[(size_t)n * 40 + cb] = make_uint2(p0, p1);
        }
        float s = 0.f, d = 0.f;
        if (ci < 10) {
            #pragma unroll
            for (int j = 0; j < 4; j++) {
                s = fmaf(acc[i * 4 + j], asrc2[cb + j], s);
                d = fmaf(acc[i * 4 + j], adst2[cb + j], d);
            }
        }
        // reduce over the 16-lane ci group (ci>=10 contribute 0)
        s += __shfl_xor(s, 1); s += __shfl_xor(s, 2);
        s += __shfl_xor(s, 4); s += __shfl_xor(s, 8);
        d += __shfl_xor(d, 1); d += __shfl_xor(d, 2);
        d += __shfl_xor(d, 4); d += __shfl_xor(d, 8);
        if (ci == 0 && n < N) { as2[n] = s; ad2[n] = d; }
    }
}

// Layer-2 aggregation + bias + log_softmax.
// 3 groups x 20 lanes: one uint gather instruction fetches THREE 80B rows.
// 12-edge chunks + ONE masked 12-wide tail iteration.
__global__ __launch_bounds__(256) void k_agg2(const ushort_t* __restrict__ gb,
                                              const float* __restrict__ as2,
                                              const float* __restrict__ ad2,
                                              const float* __restrict__ b2,
                                              const int* __restrict__ rowptr,
                                              const int* __restrict__ rowEnd,
                                              const int* __restrict__ csr,
                                              float* __restrict__ out, int N) {
    int tid = threadIdx.x, lane = tid & 63;
    int n = blockIdx.x * 4 + (tid >> 6);
    if (n >= N) return;
    int g = lane / 20, p = lane % 20;  // g==3 for lanes 60-63 (results unread)
    int c0 = 2 * p;
    const char* gbc = (const char*)gb;
    unsigned coff = (unsigned)(p << 2);
    float add = ad2[n];
    float acc0 = 0.f, acc1 = 0.f, zl = 0.f;
    {   // self loop (group 0 only)
        float e0 = as2[n] + add;
        float w = lrelu_exp(e0);
        if (g == 0) {
            unsigned int u = *(const unsigned int*)(gbc + ((unsigned)n * 80u + coff));
            acc0 = w * bf_lo(u); acc1 = w * bf_hi(u); zl = w;
        }
    }
    int j0 = rowptr[n], j1 = rowEnd[n];
    int j = j0;
    int gi0 = (0 + g) < 12 ? (0 + g) : 11;   // clamp for g==3 lanes
    int gi1 = (3 + g) < 12 ? (3 + g) : 11;
    int gi2 = (6 + g) < 12 ? (6 + g) : 11;
    int gi3 = (9 + g) < 12 ? (9 + g) : 11;
    for (; j + 12 <= j1; j += 12) {
        int cv = csr[j + (lane % 12)];   // coalesced, then bpermute
        int s0 = __shfl(cv, gi0);
        int s1 = __shfl(cv, gi1);
        int s2 = __shfl(cv, gi2);
        int s3 = __shfl(cv, gi3);
        float a0 = as2[s0], a1 = as2[s1], a2 = as2[s2], a3 = as2[s3];
        unsigned int u0 = *(const unsigned int*)(gbc + ((unsigned)s0 * 80u + coff));
        unsigned int u1 = *(const unsigned int*)(gbc + ((unsigned)s1 * 80u + coff));
        unsigned int u2 = *(const unsigned int*)(gbc + ((unsigned)s2 * 80u + coff));
        unsigned int u3 = *(const unsigned int*)(gbc + ((unsigned)s3 * 80u + coff));
        float w0 = lrelu_exp(a0 + add);
        float w1 = lrelu_exp(a1 + add);
        float w2 = lrelu_exp(a2 + add);
        float w3 = lrelu_exp(a3 + add);
        acc0 = fmaf(w0, bf_lo(u0), acc0); acc1 = fmaf(w0, bf_hi(u0), acc1); zl += w0;
        acc0 = fmaf(w1, bf_lo(u1), acc0); acc1 = fmaf(w1, bf_hi(u1), acc1); zl += w1;
        acc0 = fmaf(w2, bf_lo(u2), acc0); acc1 = fmaf(w2, bf_hi(u2), acc1); zl += w2;
        acc0 = fmaf(w3, bf_lo(u3), acc0); acc1 = fmaf(w3, bf_hi(u3), acc1); zl += w3;
    }
    int t = j1 - j;
    if (t > 0) {  // masked 12-wide tail
        int idx = lane % 12; idx = idx < t ? idx : t - 1;
        int cv = csr[j + idx];
        #pragma unroll
        for (int i = 0; i < 4; i++) {
            int e = 3 * i + g;
            int gi = e < 12 ? e : 11;
            int s = __shfl(cv, gi);  // csr[j+min(e,t-1)] for e<12
            unsigned int u = *(const unsigned int*)(gbc + ((unsigned)s * 80u + coff));
            float a = as2[s];
            float w = (e < t && g < 3) ? lrelu_exp(a + add) : 0.f;
            acc0 = fmaf(w, bf_lo(u), acc0); acc1 = fmaf(w, bf_hi(u), acc1); zl += w;
        }
    }
    // combine the 3 groups (valid at lanes 0..19)
    float A0 = acc0 + __shfl(acc0, (lane + 20) & 63) + __shfl(acc0, (lane + 40) & 63);
    float A1 = acc1 + __shfl(acc1, (lane + 20) & 63) + __shfl(acc1, (lane + 40) & 63);
    float Z  = zl + __shfl(zl, (lane + 20) & 63) + __shfl(zl, (lane + 40) & 63);
    float l0 = 0.f, l1 = 0.f;
    bool active = (lane < 20);
    if (active) {
        float inv = 1.f / (Z + 1e-16f);
        l0 = A0 * inv + b2[c0];
        l1 = A1 * inv + b2[c0 + 1];
    }
    // masked 32-lane butterfly for max and sum-exp over the 40 logits
    float mv = active ? fmaxf(l0, l1) : -INFINITY;
    #pragma unroll
    for (int ofs = 1; ofs < 32; ofs <<= 1) mv = fmaxf(mv, __shfl_xor(mv, ofs));
    float ev = active ? (__expf(l0 - mv) + __expf(l1 - mv)) : 0.f;
    #pragma unroll
    for (int ofs = 1; ofs < 32; ofs <<= 1) ev += __shfl_xor(ev, ofs);
    if (active) {
        float ls = mv + __logf(ev);
        *(float2*)&out[(size_t)n * 40 + c0] = make_float2(l0 - ls, l1 - ls);
    }
}

extern "C" void kernel_launch(void* const* d_in, const int* in_sizes, int n_in,
                              void* d_out, int out_size, void* d_ws, size_t ws_size,
                              hipStream_t stream) {
    const float* x    = (const float*)d_in[0];
    const float* topo = (const float*)d_in[1];
    const int*   ei   = (const int*)d_in[2];
    const float* W1   = (const float*)d_in[3];
    const float* a_s1 = (const float*)d_in[4];
    const float* a_d1 = (const float*)d_in[5];
    const float* b1   = (const float*)d_in[6];
    const float* W2   = (const float*)d_in[7];
    const float* a_s2 = (const float*)d_in[8];
    const float* a_d2 = (const float*)d_in[9];
    const float* b2   = (const float*)d_in[10];
    float* out = (float*)d_out;

    int N = in_sizes[0] / 128;
    int E = in_sizes[2] / 2;
    const int* esrc = ei;
    const int* edst = ei + E;
    int NBUK = (N + 255) / 256;
    size_t cap = (size_t)NBUK * BUK_CAP;

    char* ws = (char*)d_ws;
    size_t off = 0;
    auto alloc = [&](size_t bytes) -> void* {
        void* p = ws + off;
        off = (off + bytes + 255) & ~(size_t)255;
        return p;
    };
    ushort_t* h1b  = (ushort_t*)alloc((size_t)N * 64 * 2);
    float* as1     = (float*)alloc((size_t)N * 8 * 4);
    float* ad1     = (float*)alloc((size_t)N * 8 * 4);
    float* h2      = (float*)alloc((size_t)N * 64 * 4);
    ushort_t* gb   = (ushort_t*)alloc((size_t)N * 40 * 2);
    float* as2     = (float*)alloc((size_t)N * 4);
    float* ad2     = (float*)alloc((size_t)N * 4);
    int*   rowptr  = (int*)alloc((size_t)N * 4);
    int*   rowEnd  = (int*)alloc((size_t)N * 4);
    int*   csr     = (int*)alloc(cap * 4);
    unsigned int* tmp = (unsigned int*)alloc(cap * 4);
    int* gCursor   = (int*)alloc((size_t)NBUK * 4);

    k_initcur<<<(NBUK + 255) / 256, 256, 0, stream>>>(gCursor, NBUK);
    int nbin = (E + BIN_CHUNK - 1) / BIN_CHUNK;
    k_bin<<<nbin, 256, 0, stream>>>(esrc, edst, gCursor, tmp, E, NBUK);
    k_fill2<<<NBUK, 256, 0, stream>>>(tmp, gCursor, rowptr, rowEnd, csr, N);

    int nbg = (N + 63) / 64;  // 64-node GEMM tiles
    int nb4 = (N + 3) / 4;    // 1 node/wave x 4 waves/block
    k_xform1<<<nbg, 256, 0, stream>>>(x, topo, W1, a_s1, a_d1, h1b, as1, ad1, N);
    k_agg1<<<nb4, 256, 0, stream>>>(h1b, as1, ad1, b1, rowptr, rowEnd, csr, h2, N);
    k_xform2<<<nbg, 256, 0, stream>>>(h2, W2, a_s2, a_d2, gb, as2, ad2, N);
    k_agg2<<<nb4, 256, 0, stream>>>(gb, as2, ad2, b2, rowptr, rowEnd, csr, out, N);
}

// Round 13
// 337.808 us; speedup vs baseline: 1.0876x; 1.0495x over previous
//
#include <hip/hip_runtime.h>
#include <math.h>

// ---------------------------------------------------------------------------
// TopoGAT: 2-layer GAT on MI355X.
// R10: fixed-capacity bucket CSR build; padded CSR with rowptr/rowEnd.
// R5:  gather tables h1/g in bf16. R7: xform = LDS-tiled GEMM.
// R8/R9/R11: one wave-wide exp per chunk; multi-row gathers; masked
//      full-width tails (no serial remainder).
// R12: xform staging re-mapped node-minor (node=i&63): transpose ds_writes
//      now conflict-free (was 32-way on XT — 1.24e7 SQ_LDS_BANK_CONFLICT,
//      the R11 top-kernel limiter). Global staging reads become stride-128B
//      but the per-block slab (<=8.7KB) is L1-resident and fully consumed.
// ---------------------------------------------------------------------------

#define NBUK_MAX 512
#define BIN_CHUNK 8192
#define BUK_CAP 4608

typedef unsigned short ushort_t;

__device__ inline unsigned int f2bf(float f) {  // RNE fp32->bf16
    unsigned int u = __float_as_uint(f);
    u += 0x7FFFu + ((u >> 16) & 1u);
    return u >> 16;
}
__device__ inline float bf_lo(unsigned int u) {
    return __uint_as_float(u << 16);
}
__device__ inline float bf_hi(unsigned int u) {
    return __uint_as_float(u & 0xFFFF0000u);
}
__device__ inline float lrelu_exp(float q) {
    return __expf(q >= 0.f ? q : 0.2f * q);
}

__device__ inline int wave_incl_scan(int v, int lane) {
    #pragma unroll
    for (int ofs = 1; ofs < 64; ofs <<= 1) {
        int t = __shfl_up(v, ofs);
        if (lane >= ofs) v += t;
    }
    return v;
}

__global__ void k_initcur(int* __restrict__ gCursor, int NBUK) {
    int i = blockIdx.x * blockDim.x + threadIdx.x;
    if (i < NBUK) gCursor[i] = i * BUK_CAP;
}

// Bin edges into fixed-capacity bucket regions of tmp. One global atomic per
// (block,bucket); packed word = (src<<8) | (dst&255).
__global__ __launch_bounds__(256) void k_bin(const int* __restrict__ src,
                                             const int* __restrict__ dst,
                                             int* __restrict__ gCursor,
                                             unsigned int* __restrict__ tmp,
                                             int E, int NBUK) {
    __shared__ int lcnt[NBUK_MAX];
    __shared__ int lcur[NBUK_MAX];
    int tid = threadIdx.x;
    int base = blockIdx.x * BIN_CHUNK;
    for (int i = tid; i < NBUK; i += 256) lcnt[i] = 0;
    __syncthreads();
    #pragma unroll
    for (int k = 0; k < BIN_CHUNK / 256; k++) {
        int i = base + tid + k * 256;
        if (i < E) atomicAdd(&lcnt[dst[i] >> 8], 1);
    }
    __syncthreads();
    for (int b = tid; b < NBUK; b += 256) {
        int c = lcnt[b];
        lcur[b] = c ? atomicAdd(&gCursor[b], c) : 0;
    }
    __syncthreads();
    #pragma unroll
    for (int k = 0; k < BIN_CHUNK / 256; k++) {
        int i = base + tid + k * 256;
        if (i < E) {
            int d = dst[i];
            int p = atomicAdd(&lcur[d >> 8], 1);
            tmp[p] = ((unsigned int)src[i] << 8) | (unsigned int)(d & 255);
        }
    }
}

// Exact CSR fill within a bucket (padded layout, base = b*BUK_CAP).
__global__ __launch_bounds__(256) void k_fill2(const unsigned int* __restrict__ tmp,
                                               const int* __restrict__ gCursor,
                                               int* __restrict__ rowptr,
                                               int* __restrict__ rowEnd,
                                               int* __restrict__ csr, int N) {
    __shared__ int cnt[256];
    __shared__ int cur[256];
    __shared__ int wsum[4];
    int b = blockIdx.x, tid = threadIdx.x;
    int lane = tid & 63, wv = tid >> 6;
    int e0 = b * BUK_CAP;
    int e1 = gCursor[b];  // after k_bin: b*BUK_CAP + count_b
    cnt[tid] = 0;
    __syncthreads();
    for (int i = e0 + tid; i < e1; i += 256)
        atomicAdd(&cnt[tmp[i] & 255u], 1);
    __syncthreads();
    int v = cnt[tid];
    int incl = wave_incl_scan(v, lane);
    if (lane == 63) wsum[wv] = incl;
    __syncthreads();
    int woff = 0;
    for (int i = 0; i < wv; i++) woff += wsum[i];
    int excl = woff + incl - v;
    int node = b * 256 + tid;
    int start = e0 + excl;
    if (node < N) { rowptr[node] = start; rowEnd[node] = start + v; }
    cur[tid] = start;
    __syncthreads();
    for (int i = e0 + tid; i < e1; i += 256) {
        unsigned int t = tmp[i];
        int p = atomicAdd(&cur[t & 255u], 1);
        csr[p] = (int)(t >> 8);
    }
}

// h1b[n][64](bf16) = [x[n]|topo[n]] @ W1 ; as1/ad1 from fp32 accumulators.
// Block = 64 nodes x 64 cols GEMM tile, K=136. W1 + xT staged in LDS.
// Staging is node-minor: 64 lanes hold 64 distinct nodes -> conflict-free
// transpose writes (4 consecutive-dword ds_write_b32 per lane).
__global__ __launch_bounds__(256) void k_xform1(const float* __restrict__ x,
                                                const float* __restrict__ topo,
                                                const float* __restrict__ W1,
                                                const float* __restrict__ asrc,
                                                const float* __restrict__ adst,
                                                ushort_t* __restrict__ h1b,
                                                float* __restrict__ as1,
                                                float* __restrict__ ad1, int N) {
    __shared__ float XT[136 * 64];  // XT[k][node]
    __shared__ float WS[136 * 64];  // WS[k][col]
    int tid = threadIdx.x;
    int n0 = blockIdx.x * 64;
    {   // stage W1: 8704 floats = 2176 float4 (once per block)
        const float4* W4 = (const float4*)W1;
        float4* WS4 = (float4*)WS;
        for (int i = tid; i < 2176; i += 256) WS4[i] = W4[i];
    }
    {   // stage x transposed, node-minor: i = k4*64 + node
        const float4* x4 = (const float4*)x;
        for (int i = tid; i < 2048; i += 256) {
            int node = i & 63, k4 = i >> 6;
            int gn = n0 + node; if (gn > N - 1) gn = N - 1;
            float4 v = x4[(size_t)gn * 32 + k4];
            int k = k4 * 4;
            XT[(k + 0) * 64 + node] = v.x;
            XT[(k + 1) * 64 + node] = v.y;
            XT[(k + 2) * 64 + node] = v.z;
            XT[(k + 3) * 64 + node] = v.w;
        }
        // topo rows 128..135: i = j4*64 + node, j4 in {0,1}
        const float4* t4 = (const float4*)topo;
        if (tid < 128) {
            int node = tid & 63, j4 = tid >> 6;
            int gn = n0 + node; if (gn > N - 1) gn = N - 1;
            float4 v = t4[(size_t)gn * 2 + j4];
            int k = 128 + j4 * 4;
            XT[(k + 0) * 64 + node] = v.x;
            XT[(k + 1) * 64 + node] = v.y;
            XT[(k + 2) * 64 + node] = v.z;
            XT[(k + 3) * 64 + node] = v.w;
        }
    }
    __syncthreads();
    int ci = tid & 15, ni = tid >> 4;
    int nb = ni * 4, cb = ci * 4;
    float acc[16];
    #pragma unroll
    for (int i = 0; i < 16; i++) acc[i] = 0.f;
    #pragma unroll 4
    for (int k = 0; k < 136; k++) {
        float4 xv = *(const float4*)&XT[k * 64 + nb];
        float4 wv = *(const float4*)&WS[k * 64 + cb];
        acc[0]  = fmaf(xv.x, wv.x, acc[0]);  acc[1]  = fmaf(xv.x, wv.y, acc[1]);
        acc[2]  = fmaf(xv.x, wv.z, acc[2]);  acc[3]  = fmaf(xv.x, wv.w, acc[3]);
        acc[4]  = fmaf(xv.y, wv.x, acc[4]);  acc[5]  = fmaf(xv.y, wv.y, acc[5]);
        acc[6]  = fmaf(xv.y, wv.z, acc[6]);  acc[7]  = fmaf(xv.y, wv.w, acc[7]);
        acc[8]  = fmaf(xv.z, wv.x, acc[8]);  acc[9]  = fmaf(xv.z, wv.y, acc[9]);
        acc[10] = fmaf(xv.z, wv.z, acc[10]); acc[11] = fmaf(xv.z, wv.w, acc[11]);
        acc[12] = fmaf(xv.w, wv.x, acc[12]); acc[13] = fmaf(xv.w, wv.y, acc[13]);
        acc[14] = fmaf(xv.w, wv.z, acc[14]); acc[15] = fmaf(xv.w, wv.w, acc[15]);
    }
    int head = cb >> 3;  // cols cb..cb+3 lie in one head (cb multiple of 4)
    #pragma unroll
    for (int i = 0; i < 4; i++) {
        int n = n0 + nb + i;
        unsigned int p0 = f2bf(acc[i * 4 + 0]) | (f2bf(acc[i * 4 + 1]) << 16);
        unsigned int p1 = f2bf(acc[i * 4 + 2]) | (f2bf(acc[i * 4 + 3]) << 16);
        if (n < N) *(uint2*)&h1b[(size_t)n * 64 + cb] = make_uint2(p0, p1);
        float s = 0.f, d = 0.f;
        #pragma unroll
        for (int j = 0; j < 4; j++) {
            s = fmaf(acc[i * 4 + j], asrc[cb + j], s);
            d = fmaf(acc[i * 4 + j], adst[cb + j], d);
        }
        s += __shfl_xor(s, 1);  // combine the two half-head threads
        d += __shfl_xor(d, 1);
        if ((ci & 1) == 0 && n < N) {
            as1[n * 8 + head] = s;
            ad1[n * 8 + head] = d;
        }
    }
}

// Per-dst softmax-weighted aggregation, layer 1 (+ implicit self loop).
// 2 groups x 32 lanes: one uint gather instruction fetches TWO full 128B
// rows. 8-edge chunks + ONE masked 8-wide tail iteration.
__global__ __launch_bounds__(256) void k_agg1(const ushort_t* __restrict__ h1b,
                                              const float* __restrict__ as1,
                                              const float* __restrict__ ad1,
                                              const float* __restrict__ b1,
                                              const int* __restrict__ rowptr,
                                              const int* __restrict__ rowEnd,
                                              const int* __restrict__ csr,
                                              float* __restrict__ h2, int N) {
    int tid = threadIdx.x, lane = tid & 63;
    int n = blockIdx.x * 4 + (tid >> 6);
    if (n >= N) return;
    int g = lane >> 5, p = lane & 31;
    int c0 = 2 * p;
    int h = p >> 2;  // head of cols c0, c0+1
    const char* h1c = (const char*)h1b;
    const char* as1c = (const char*)as1;
    unsigned coff = (unsigned)(p << 2);   // c0 * 2 bytes
    unsigned hoff = (unsigned)(h << 2);   // head * 4 bytes
    float ad_dl = ad1[n * 8 + h];
    float acc0 = 0.f, acc1 = 0.f, zl = 0.f;
    {   // self loop (group 0 only)
        float e0 = as1[n * 8 + h] + ad_dl;
        float w = lrelu_exp(e0);
        if (g == 0) {
            unsigned int u = *(const unsigned int*)(h1c + (((unsigned)n << 7) + coff));
            acc0 = w * bf_lo(u); acc1 = w * bf_hi(u); zl = w;
        }
    }
    int j0 = rowptr[n], j1 = rowEnd[n];
    int j = j0;
    for (; j + 8 <= j1; j += 8) {
        int cv = csr[j + (lane & 7)];           // coalesced, then bpermute
        int s0 = __shfl(cv, 0 + g);
        int s1 = __shfl(cv, 2 + g);
        int s2 = __shfl(cv, 4 + g);
        int s3 = __shfl(cv, 6 + g);
        unsigned int u0 = *(const unsigned int*)(h1c + (((unsigned)s0 << 7) + coff));
        unsigned int u1 = *(const unsigned int*)(h1c + (((unsigned)s1 << 7) + coff));
        unsigned int u2 = *(const unsigned int*)(h1c + (((unsigned)s2 << 7) + coff));
        unsigned int u3 = *(const unsigned int*)(h1c + (((unsigned)s3 << 7) + coff));
        float a0 = *(const float*)(as1c + (((unsigned)s0 << 5) + hoff));
        float a1 = *(const float*)(as1c + (((unsigned)s1 << 5) + hoff));
        float a2 = *(const float*)(as1c + (((unsigned)s2 << 5) + hoff));
        float a3 = *(const float*)(as1c + (((unsigned)s3 << 5) + hoff));
        float w0 = lrelu_exp(a0 + ad_dl);
        float w1 = lrelu_exp(a1 + ad_dl);
        float w2 = lrelu_exp(a2 + ad_dl);
        float w3 = lrelu_exp(a3 + ad_dl);
        acc0 = fmaf(w0, bf_lo(u0), acc0); acc1 = fmaf(w0, bf_hi(u0), acc1); zl += w0;
        acc0 = fmaf(w1, bf_lo(u1), acc0); acc1 = fmaf(w1, bf_hi(u1), acc1); zl += w1;
        acc0 = fmaf(w2, bf_lo(u2), acc0); acc1 = fmaf(w2, bf_hi(u2), acc1); zl += w2;
        acc0 = fmaf(w3, bf_lo(u3), acc0); acc1 = fmaf(w3, bf_hi(u3), acc1); zl += w3;
    }
    int t = j1 - j;
    if (t > 0) {  // masked 8-wide tail: clamped index, zeroed weights
        int idx = lane & 7; idx = idx < t ? idx : t - 1;
        int cv = csr[j + idx];
        #pragma unroll
        for (int i = 0; i < 4; i++) {
            int e = 2 * i + g;
            int s = __shfl(cv, e);  // lane e holds csr[j+min(e,t-1)]
            unsigned int u = *(const unsigned int*)(h1c + (((unsigned)s << 7) + coff));
            float a = *(const float*)(as1c + (((unsigned)s << 5) + hoff));
            float w = (e < t) ? lrelu_exp(a + ad_dl) : 0.f;
            acc0 = fmaf(w, bf_lo(u), acc0); acc1 = fmaf(w, bf_hi(u), acc1); zl += w;
        }
    }
    float A0 = acc0 + __shfl_xor(acc0, 32);
    float A1 = acc1 + __shfl_xor(acc1, 32);
    float Z  = zl + __shfl_xor(zl, 32);
    if (g == 0) {
        float inv = 1.f / (Z + 1e-16f);
        float v0 = A0 * inv + b1[c0];
        float v1 = A1 * inv + b1[c0 + 1];
        v0 = v0 > 0.f ? v0 : (__expf(v0) - 1.f);
        v1 = v1 > 0.f ? v1 : (__expf(v1) - 1.f);
        *(float2*)&h2[(size_t)n * 64 + c0] = make_float2(v0, v1);
    }
}

// gb[n][40](bf16) = h2[n] @ W2 ; as2/ad2 from fp32 accumulators.
// Block = 64 nodes x 40 cols GEMM tile, K=64. Node-minor staging.
__global__ __launch_bounds__(256) void k_xform2(const float* __restrict__ h2,
                                                const float* __restrict__ W2,
                                                const float* __restrict__ asrc2,
                                                const float* __restrict__ adst2,
                                                ushort_t* __restrict__ gb,
                                                float* __restrict__ as2,
                                                float* __restrict__ ad2, int N) {
    __shared__ float XT[64 * 64];  // h2T[k][node]
    __shared__ float WS[64 * 40];  // WS[k][col]
    int tid = threadIdx.x;
    int n0 = blockIdx.x * 64;
    {   // stage W2: 2560 floats = 640 float4
        const float4* W4 = (const float4*)W2;
        float4* WS4 = (float4*)WS;
        for (int i = tid; i < 640; i += 256) WS4[i] = W4[i];
    }
    {   // stage h2 transposed, node-minor: i = k4*64 + node
        const float4* h4 = (const float4*)h2;
        for (int i = tid; i < 1024; i += 256) {
            int node = i & 63, k4 = i >> 6;
            int gn = n0 + node; if (gn > N - 1) gn = N - 1;
            float4 v = h4[(size_t)gn * 16 + k4];
            int k = k4 * 4;
            XT[(k + 0) * 64 + node] = v.x;
            XT[(k + 1) * 64 + node] = v.y;
            XT[(k + 2) * 64 + node] = v.z;
            XT[(k + 3) * 64 + node] = v.w;
        }
    }
    __syncthreads();
    int ci = tid & 15, ni = tid >> 4;
    int nb = ni * 4, cb = ci * 4;
    float acc[16];
    #pragma unroll
    for (int i = 0; i < 16; i++) acc[i] = 0.f;
    if (ci < 10) {
        #pragma unroll 4
        for (int k = 0; k < 64; k++) {
            float4 xv = *(const float4*)&XT[k * 64 + nb];
            float4 wv = *(const float4*)&WS[k * 40 + cb];
            acc[0]  = fmaf(xv.x, wv.x, acc[0]);  acc[1]  = fmaf(xv.x, wv.y, acc[1]);
            acc[2]  = fmaf(xv.x, wv.z, acc[2]);  acc[3]  = fmaf(xv.x, wv.w, acc[3]);
            acc[4]  = fmaf(xv.y, wv.x, acc[4]);  acc[5]  = fmaf(xv.y, wv.y, acc[5]);
            acc[6]  = fmaf(xv.y, wv.z, acc[6]);  acc[7]  = fmaf(xv.y, wv.w, acc[7]);
            acc[8]  = fmaf(xv.z, wv.x, acc[8]);  acc[9]  = fmaf(xv.z, wv.y, acc[9]);
            acc[10] = fmaf(xv.z, wv.z, acc[10]); acc[11] = fmaf(xv.z, wv.w, acc[11]);
            acc[12] = fmaf(xv.w, wv.x, acc[12]); acc[13] = fmaf(xv.w, wv.y, acc[13]);
            acc[14] = fmaf(xv.w, wv.z, acc[14]); acc[15] = fmaf(xv.w, wv.w, acc[15]);
        }
    }
    #pragma unroll
    for (int i = 0; i < 4; i++) {
        int n = n0 + nb + i;
        if (ci < 10 && n < N) {
            unsigned int p0 = f2bf(acc[i * 4 + 0]) | (f2bf(acc[i * 4 + 1]) << 16);
            unsigned int p1 = f2bf(acc[i * 4 + 2]) | (f2bf(acc[i * 4 + 3]) << 16);
            *(uint2*)&gb[(size_t)n * 40 + cb] = make_uint2(p0, p1);
        }
        float s = 0.f, d = 0.f;
        if (ci < 10) {
            #pragma unroll
            for (int j = 0; j < 4; j++) {
                s = fmaf(acc[i * 4 + j], asrc2[cb + j], s);
                d = fmaf(acc[i * 4 + j], adst2[cb + j], d);
            }
        }
        // reduce over the 16-lane ci group (ci>=10 contribute 0)
        s += __shfl_xor(s, 1); s += __shfl_xor(s, 2);
        s += __shfl_xor(s, 4); s += __shfl_xor(s, 8);
        d += __shfl_xor(d, 1); d += __shfl_xor(d, 2);
        d += __shfl_xor(d, 4); d += __shfl_xor(d, 8);
        if (ci == 0 && n < N) { as2[n] = s; ad2[n] = d; }
    }
}

// Layer-2 aggregation + bias + log_softmax.
// 3 groups x 20 lanes: one uint gather instruction fetches THREE 80B rows.
// 12-edge chunks + ONE masked 12-wide tail iteration.
__global__ __launch_bounds__(256) void k_agg2(const ushort_t* __restrict__ gb,
                                              const float* __restrict__ as2,
                                              const float* __restrict__ ad2,
                                              const float* __restrict__ b2,
                                              const int* __restrict__ rowptr,
                                              const int* __restrict__ rowEnd,
                                              const int* __restrict__ csr,
                                              float* __restrict__ out, int N) {
    int tid = threadIdx.x, lane = tid & 63;
    int n = blockIdx.x * 4 + (tid >> 6);
    if (n >= N) return;
    int g = lane / 20, p = lane % 20;  // g==3 for lanes 60-63 (results unread)
    int c0 = 2 * p;
    const char* gbc = (const char*)gb;
    unsigned coff = (unsigned)(p << 2);
    float add = ad2[n];
    float acc0 = 0.f, acc1 = 0.f, zl = 0.f;
    {   // self loop (group 0 only)
        float e0 = as2[n] + add;
        float w = lrelu_exp(e0);
        if (g == 0) {
            unsigned int u = *(const unsigned int*)(gbc + ((unsigned)n * 80u + coff));
            acc0 = w * bf_lo(u); acc1 = w * bf_hi(u); zl = w;
        }
    }
    int j0 = rowptr[n], j1 = rowEnd[n];
    int j = j0;
    int gi0 = (0 + g) < 12 ? (0 + g) : 11;   // clamp for g==3 lanes
    int gi1 = (3 + g) < 12 ? (3 + g) : 11;
    int gi2 = (6 + g) < 12 ? (6 + g) : 11;
    int gi3 = (9 + g) < 12 ? (9 + g) : 11;
    for (; j + 12 <= j1; j += 12) {
        int cv = csr[j + (lane % 12)];   // coalesced, then bpermute
        int s0 = __shfl(cv, gi0);
        int s1 = __shfl(cv, gi1);
        int s2 = __shfl(cv, gi2);
        int s3 = __shfl(cv, gi3);
        float a0 = as2[s0], a1 = as2[s1], a2 = as2[s2], a3 = as2[s3];
        unsigned int u0 = *(const unsigned int*)(gbc + ((unsigned)s0 * 80u + coff));
        unsigned int u1 = *(const unsigned int*)(gbc + ((unsigned)s1 * 80u + coff));
        unsigned int u2 = *(const unsigned int*)(gbc + ((unsigned)s2 * 80u + coff));
        unsigned int u3 = *(const unsigned int*)(gbc + ((unsigned)s3 * 80u + coff));
        float w0 = lrelu_exp(a0 + add);
        float w1 = lrelu_exp(a1 + add);
        float w2 = lrelu_exp(a2 + add);
        float w3 = lrelu_exp(a3 + add);
        acc0 = fmaf(w0, bf_lo(u0), acc0); acc1 = fmaf(w0, bf_hi(u0), acc1); zl += w0;
        acc0 = fmaf(w1, bf_lo(u1), acc0); acc1 = fmaf(w1, bf_hi(u1), acc1); zl += w1;
        acc0 = fmaf(w2, bf_lo(u2), acc0); acc1 = fmaf(w2, bf_hi(u2), acc1); zl += w2;
        acc0 = fmaf(w3, bf_lo(u3), acc0); acc1 = fmaf(w3, bf_hi(u3), acc1); zl += w3;
    }
    int t = j1 - j;
    if (t > 0) {  // masked 12-wide tail
        int idx = lane % 12; idx = idx < t ? idx : t - 1;
        int cv = csr[j + idx];
        #pragma unroll
        for (int i = 0; i < 4; i++) {
            int e = 3 * i + g;
            int gi = e < 12 ? e : 11;
            int s = __shfl(cv, gi);  // csr[j+min(e,t-1)] for e<12
            unsigned int u = *(const unsigned int*)(gbc + ((unsigned)s * 80u + coff));
            float a = as2[s];
            float w = (e < t && g < 3) ? lrelu_exp(a + add) : 0.f;
            acc0 = fmaf(w, bf_lo(u), acc0); acc1 = fmaf(w, bf_hi(u), acc1); zl += w;
        }
    }
    // combine the 3 groups (valid at lanes 0..19)
    float A0 = acc0 + __shfl(acc0, (lane + 20) & 63) + __shfl(acc0, (lane + 40) & 63);
    float A1 = acc1 + __shfl(acc1, (lane + 20) & 63) + __shfl(acc1, (lane + 40) & 63);
    float Z  = zl + __shfl(zl, (lane + 20) & 63) + __shfl(zl, (lane + 40) & 63);
    float l0 = 0.f, l1 = 0.f;
    bool active = (lane < 20);
    if (active) {
        float inv = 1.f / (Z + 1e-16f);
        l0 = A0 * inv + b2[c0];
        l1 = A1 * inv + b2[c0 + 1];
    }
    // masked 32-lane butterfly for max and sum-exp over the 40 logits
    float mv = active ? fmaxf(l0, l1) : -INFINITY;
    #pragma unroll
    for (int ofs = 1; ofs < 32; ofs <<= 1) mv = fmaxf(mv, __shfl_xor(mv, ofs));
    float ev = active ? (__expf(l0 - mv) + __expf(l1 - mv)) : 0.f;
    #pragma unroll
    for (int ofs = 1; ofs < 32; ofs <<= 1) ev += __shfl_xor(ev, ofs);
    if (active) {
        float ls = mv + __logf(ev);
        *(float2*)&out[(size_t)n * 40 + c0] = make_float2(l0 - ls, l1 - ls);
    }
}

extern "C" void kernel_launch(void* const* d_in, const int* in_sizes, int n_in,
                              void* d_out, int out_size, void* d_ws, size_t ws_size,
                              hipStream_t stream) {
    const float* x    = (const float*)d_in[0];
    const float* topo = (const float*)d_in[1];
    const int*   ei   = (const int*)d_in[2];
    const float* W1   = (const float*)d_in[3];
    const float* a_s1 = (const float*)d_in[4];
    const float* a_d1 = (const float*)d_in[5];
    const float* b1   = (const float*)d_in[6];
    const float* W2   = (const float*)d_in[7];
    const float* a_s2 = (const float*)d_in[8];
    const float* a_d2 = (const float*)d_in[9];
    const float* b2   = (const float*)d_in[10];
    float* out = (float*)d_out;

    int N = in_sizes[0] / 128;
    int E = in_sizes[2] / 2;
    const int* esrc = ei;
    const int* edst = ei + E;
    int NBUK = (N + 255) / 256;
    size_t cap = (size_t)NBUK * BUK_CAP;

    char* ws = (char*)d_ws;
    size_t off = 0;
    auto alloc = [&](size_t bytes) -> void* {
        void* p = ws + off;
        off = (off + bytes + 255) & ~(size_t)255;
        return p;
    };
    ushort_t* h1b  = (ushort_t*)alloc((size_t)N * 64 * 2);
    float* as1     = (float*)alloc((size_t)N * 8 * 4);
    float* ad1     = (float*)alloc((size_t)N * 8 * 4);
    float* h2      = (float*)alloc((size_t)N * 64 * 4);
    ushort_t* gb   = (ushort_t*)alloc((size_t)N * 40 * 2);
    float* as2     = (float*)alloc((size_t)N * 4);
    float* ad2     = (float*)alloc((size_t)N * 4);
    int*   rowptr  = (int*)alloc((size_t)N * 4);
    int*   rowEnd  = (int*)alloc((size_t)N * 4);
    int*   csr     = (int*)alloc(cap * 4);
    unsigned int* tmp = (unsigned int*)alloc(cap * 4);
    int* gCursor   = (int*)alloc((size_t)NBUK * 4);

    k_initcur<<<(NBUK + 255) / 256, 256, 0, stream>>>(gCursor, NBUK);
    int nbin = (E + BIN_CHUNK - 1) / BIN_CHUNK;
    k_bin<<<nbin, 256, 0, stream>>>(esrc, edst, gCursor, tmp, E, NBUK);
    k_fill2<<<NBUK, 256, 0, stream>>>(tmp, gCursor, rowptr, rowEnd, csr, N);

    int nbg = (N + 63) / 64;  // 64-node GEMM tiles
    int nb4 = (N + 3) / 4;    // 1 node/wave x 4 waves/block
    k_xform1<<<nbg, 256, 0, stream>>>(x, topo, W1, a_s1, a_d1, h1b, as1, ad1, N);
    k_agg1<<<nb4, 256, 0, stream>>>(h1b, as1, ad1, b1, rowptr, rowEnd, csr, h2, N);
    k_xform2<<<nbg, 256, 0, stream>>>(h2, W2, a_s2, a_d2, gb, as2, ad2, N);
    k_agg2<<<nb4, 256, 0, stream>>>(gb, as2, ad2, b2, rowptr, rowEnd, csr, out, N);
}

// Round 14
// 323.231 us; speedup vs baseline: 1.1367x; 1.0451x over previous
//
#include <hip/hip_runtime.h>
#include <math.h>

// ---------------------------------------------------------------------------
// TopoGAT: 2-layer GAT on MI355X.
// R10: fixed-capacity bucket CSR build; padded CSR with rowptr/rowEnd.
// R5:  gather tables h1/g in bf16. R7: xform = LDS-tiled GEMM.
// R12: node-minor staging (conflict-free transpose writes).
// R9/R11: multi-row gathers (agg1 2x32 lanes -> 2 full 128B rows/instr;
//      agg2 3x20 -> 3 x 80B rows/instr); masked full-width tails.
// R13: R8's one-wave-wide-exp restored INSIDE the R9 structure (it was lost
//      in the restructure): agg2 computes all 12 chunk weights with ONE
//      as2 load + ONE exp per lane (was 4 loads + 4 exps, 20x redundant);
//      agg1 uses the (edge=lane>>3, head=lane&7) weight-lane mapping — one
//      64-wide as1 gather + one exp per 8-edge chunk. Weights distributed
//      via shfl (DS pipe, idle here).
// ---------------------------------------------------------------------------

#define NBUK_MAX 512
#define BIN_CHUNK 8192
#define BUK_CAP 4608

typedef unsigned short ushort_t;

__device__ inline unsigned int f2bf(float f) {  // RNE fp32->bf16
    unsigned int u = __float_as_uint(f);
    u += 0x7FFFu + ((u >> 16) & 1u);
    return u >> 16;
}
__device__ inline float bf_lo(unsigned int u) {
    return __uint_as_float(u << 16);
}
__device__ inline float bf_hi(unsigned int u) {
    return __uint_as_float(u & 0xFFFF0000u);
}
__device__ inline float lrelu_exp(float q) {
    return __expf(q >= 0.f ? q : 0.2f * q);
}

__device__ inline int wave_incl_scan(int v, int lane) {
    #pragma unroll
    for (int ofs = 1; ofs < 64; ofs <<= 1) {
        int t = __shfl_up(v, ofs);
        if (lane >= ofs) v += t;
    }
    return v;
}

__global__ void k_initcur(int* __restrict__ gCursor, int NBUK) {
    int i = blockIdx.x * blockDim.x + threadIdx.x;
    if (i < NBUK) gCursor[i] = i * BUK_CAP;
}

// Bin edges into fixed-capacity bucket regions of tmp. One global atomic per
// (block,bucket); packed word = (src<<8) | (dst&255).
__global__ __launch_bounds__(256) void k_bin(const int* __restrict__ src,
                                             const int* __restrict__ dst,
                                             int* __restrict__ gCursor,
                                             unsigned int* __restrict__ tmp,
                                             int E, int NBUK) {
    __shared__ int lcnt[NBUK_MAX];
    __shared__ int lcur[NBUK_MAX];
    int tid = threadIdx.x;
    int base = blockIdx.x * BIN_CHUNK;
    for (int i = tid; i < NBUK; i += 256) lcnt[i] = 0;
    __syncthreads();
    #pragma unroll
    for (int k = 0; k < BIN_CHUNK / 256; k++) {
        int i = base + tid + k * 256;
        if (i < E) atomicAdd(&lcnt[dst[i] >> 8], 1);
    }
    __syncthreads();
    for (int b = tid; b < NBUK; b += 256) {
        int c = lcnt[b];
        lcur[b] = c ? atomicAdd(&gCursor[b], c) : 0;
    }
    __syncthreads();
    #pragma unroll
    for (int k = 0; k < BIN_CHUNK / 256; k++) {
        int i = base + tid + k * 256;
        if (i < E) {
            int d = dst[i];
            int p = atomicAdd(&lcur[d >> 8], 1);
            tmp[p] = ((unsigned int)src[i] << 8) | (unsigned int)(d & 255);
        }
    }
}

// Exact CSR fill within a bucket (padded layout, base = b*BUK_CAP).
__global__ __launch_bounds__(256) void k_fill2(const unsigned int* __restrict__ tmp,
                                               const int* __restrict__ gCursor,
                                               int* __restrict__ rowptr,
                                               int* __restrict__ rowEnd,
                                               int* __restrict__ csr, int N) {
    __shared__ int cnt[256];
    __shared__ int cur[256];
    __shared__ int wsum[4];
    int b = blockIdx.x, tid = threadIdx.x;
    int lane = tid & 63, wv = tid >> 6;
    int e0 = b * BUK_CAP;
    int e1 = gCursor[b];  // after k_bin: b*BUK_CAP + count_b
    cnt[tid] = 0;
    __syncthreads();
    for (int i = e0 + tid; i < e1; i += 256)
        atomicAdd(&cnt[tmp[i] & 255u], 1);
    __syncthreads();
    int v = cnt[tid];
    int incl = wave_incl_scan(v, lane);
    if (lane == 63) wsum[wv] = incl;
    __syncthreads();
    int woff = 0;
    for (int i = 0; i < wv; i++) woff += wsum[i];
    int excl = woff + incl - v;
    int node = b * 256 + tid;
    int start = e0 + excl;
    if (node < N) { rowptr[node] = start; rowEnd[node] = start + v; }
    cur[tid] = start;
    __syncthreads();
    for (int i = e0 + tid; i < e1; i += 256) {
        unsigned int t = tmp[i];
        int p = atomicAdd(&cur[t & 255u], 1);
        csr[p] = (int)(t >> 8);
    }
}

// h1b[n][64](bf16) = [x[n]|topo[n]] @ W1 ; as1/ad1 from fp32 accumulators.
// Block = 64 nodes x 64 cols GEMM tile, K=136. W1 + xT staged in LDS,
// node-minor (conflict-free transpose writes).
__global__ __launch_bounds__(256) void k_xform1(const float* __restrict__ x,
                                                const float* __restrict__ topo,
                                                const float* __restrict__ W1,
                                                const float* __restrict__ asrc,
                                                const float* __restrict__ adst,
                                                ushort_t* __restrict__ h1b,
                                                float* __restrict__ as1,
                                                float* __restrict__ ad1, int N) {
    __shared__ float XT[136 * 64];  // XT[k][node]
    __shared__ float WS[136 * 64];  // WS[k][col]
    int tid = threadIdx.x;
    int n0 = blockIdx.x * 64;
    {   // stage W1: 8704 floats = 2176 float4 (once per block)
        const float4* W4 = (const float4*)W1;
        float4* WS4 = (float4*)WS;
        for (int i = tid; i < 2176; i += 256) WS4[i] = W4[i];
    }
    {   // stage x transposed, node-minor: i = k4*64 + node
        const float4* x4 = (const float4*)x;
        for (int i = tid; i < 2048; i += 256) {
            int node = i & 63, k4 = i >> 6;
            int gn = n0 + node; if (gn > N - 1) gn = N - 1;
            float4 v = x4[(size_t)gn * 32 + k4];
            int k = k4 * 4;
            XT[(k + 0) * 64 + node] = v.x;
            XT[(k + 1) * 64 + node] = v.y;
            XT[(k + 2) * 64 + node] = v.z;
            XT[(k + 3) * 64 + node] = v.w;
        }
        // topo rows 128..135: i = j4*64 + node, j4 in {0,1}
        const float4* t4 = (const float4*)topo;
        if (tid < 128) {
            int node = tid & 63, j4 = tid >> 6;
            int gn = n0 + node; if (gn > N - 1) gn = N - 1;
            float4 v = t4[(size_t)gn * 2 + j4];
            int k = 128 + j4 * 4;
            XT[(k + 0) * 64 + node] = v.x;
            XT[(k + 1) * 64 + node] = v.y;
            XT[(k + 2) * 64 + node] = v.z;
            XT[(k + 3) * 64 + node] = v.w;
        }
    }
    __syncthreads();
    int ci = tid & 15, ni = tid >> 4;
    int nb = ni * 4, cb = ci * 4;
    float acc[16];
    #pragma unroll
    for (int i = 0; i < 16; i++) acc[i] = 0.f;
    #pragma unroll 4
    for (int k = 0; k < 136; k++) {
        float4 xv = *(const float4*)&XT[k * 64 + nb];
        float4 wv = *(const float4*)&WS[k * 64 + cb];
        acc[0]  = fmaf(xv.x, wv.x, acc[0]);  acc[1]  = fmaf(xv.x, wv.y, acc[1]);
        acc[2]  = fmaf(xv.x, wv.z, acc[2]);  acc[3]  = fmaf(xv.x, wv.w, acc[3]);
        acc[4]  = fmaf(xv.y, wv.x, acc[4]);  acc[5]  = fmaf(xv.y, wv.y, acc[5]);
        acc[6]  = fmaf(xv.y, wv.z, acc[6]);  acc[7]  = fmaf(xv.y, wv.w, acc[7]);
        acc[8]  = fmaf(xv.z, wv.x, acc[8]);  acc[9]  = fmaf(xv.z, wv.y, acc[9]);
        acc[10] = fmaf(xv.z, wv.z, acc[10]); acc[11] = fmaf(xv.z, wv.w, acc[11]);
        acc[12] = fmaf(xv.w, wv.x, acc[12]); acc[13] = fmaf(xv.w, wv.y, acc[13]);
        acc[14] = fmaf(xv.w, wv.z, acc[14]); acc[15] = fmaf(xv.w, wv.w, acc[15]);
    }
    int head = cb >> 3;  // cols cb..cb+3 lie in one head (cb multiple of 4)
    #pragma unroll
    for (int i = 0; i < 4; i++) {
        int n = n0 + nb + i;
        unsigned int p0 = f2bf(acc[i * 4 + 0]) | (f2bf(acc[i * 4 + 1]) << 16);
        unsigned int p1 = f2bf(acc[i * 4 + 2]) | (f2bf(acc[i * 4 + 3]) << 16);
        if (n < N) *(uint2*)&h1b[(size_t)n * 64 + cb] = make_uint2(p0, p1);
        float s = 0.f, d = 0.f;
        #pragma unroll
        for (int j = 0; j < 4; j++) {
            s = fmaf(acc[i * 4 + j], asrc[cb + j], s);
            d = fmaf(acc[i * 4 + j], adst[cb + j], d);
        }
        s += __shfl_xor(s, 1);  // combine the two half-head threads
        d += __shfl_xor(d, 1);
        if ((ci & 1) == 0 && n < N) {
            as1[n * 8 + head] = s;
            ad1[n * 8 + head] = d;
        }
    }
}

// Per-dst softmax-weighted aggregation, layer 1 (+ implicit self loop).
// 2 groups x 32 lanes -> TWO full 128B rows per gather instruction.
// Weight-lane mapping (edge=lane>>3, head=lane&7): ONE as1 gather + ONE exp
// per 8-edge chunk; weights distributed via shfl.
__global__ __launch_bounds__(256) void k_agg1(const ushort_t* __restrict__ h1b,
                                              const float* __restrict__ as1,
                                              const float* __restrict__ ad1,
                                              const float* __restrict__ b1,
                                              const int* __restrict__ rowptr,
                                              const int* __restrict__ rowEnd,
                                              const int* __restrict__ csr,
                                              float* __restrict__ h2, int N) {
    int tid = threadIdx.x, lane = tid & 63;
    int n = blockIdx.x * 4 + (tid >> 6);
    if (n >= N) return;
    int g = lane >> 5, p = lane & 31;
    int c0 = 2 * p;
    int h = p >> 2;  // head of cols c0, c0+1
    const char* h1c = (const char*)h1b;
    const char* as1c = (const char*)as1;
    unsigned coff = (unsigned)(p << 2);        // c0 * 2 bytes
    unsigned whoff = (unsigned)((lane & 7) << 2);  // weight-lane head * 4 bytes
    int wbase = (g << 3) + h;  // shuffle source base for this compute lane
    float ad_dl = ad1[n * 8 + h];
    float adv = ad1[n * 8 + (lane & 7)];  // weight-lane view
    float acc0 = 0.f, acc1 = 0.f, zl = 0.f;
    {   // self loop (group 0 only)
        float e0 = as1[n * 8 + h] + ad_dl;
        float w = lrelu_exp(e0);
        if (g == 0) {
            unsigned int u = *(const unsigned int*)(h1c + (((unsigned)n << 7) + coff));
            acc0 = w * bf_lo(u); acc1 = w * bf_hi(u); zl = w;
        }
    }
    int j0 = rowptr[n], j1 = rowEnd[n];
    int j = j0;
    for (; j + 8 <= j1; j += 8) {
        int cv = csr[j + (lane & 7)];           // coalesced, then bpermute
        // one wave-wide weight computation: lane = (edge<<3)|head
        int se = __shfl(cv, lane >> 3);
        float av = *(const float*)(as1c + (((unsigned)se << 5) + whoff));
        float wall = lrelu_exp(av + adv);
        int s0 = __shfl(cv, 0 + g);
        int s1 = __shfl(cv, 2 + g);
        int s2 = __shfl(cv, 4 + g);
        int s3 = __shfl(cv, 6 + g);
        unsigned int u0 = *(const unsigned int*)(h1c + (((unsigned)s0 << 7) + coff));
        unsigned int u1 = *(const unsigned int*)(h1c + (((unsigned)s1 << 7) + coff));
        unsigned int u2 = *(const unsigned int*)(h1c + (((unsigned)s2 << 7) + coff));
        unsigned int u3 = *(const unsigned int*)(h1c + (((unsigned)s3 << 7) + coff));
        float w0 = __shfl(wall, wbase);        // edge g,   head h
        float w1 = __shfl(wall, wbase + 16);   // edge 2+g
        float w2 = __shfl(wall, wbase + 32);   // edge 4+g
        float w3 = __shfl(wall, wbase + 48);   // edge 6+g
        acc0 = fmaf(w0, bf_lo(u0), acc0); acc1 = fmaf(w0, bf_hi(u0), acc1); zl += w0;
        acc0 = fmaf(w1, bf_lo(u1), acc0); acc1 = fmaf(w1, bf_hi(u1), acc1); zl += w1;
        acc0 = fmaf(w2, bf_lo(u2), acc0); acc1 = fmaf(w2, bf_hi(u2), acc1); zl += w2;
        acc0 = fmaf(w3, bf_lo(u3), acc0); acc1 = fmaf(w3, bf_hi(u3), acc1); zl += w3;
    }
    int t = j1 - j;
    if (t > 0) {  // masked 8-wide tail: clamped index, zeroed weights
        int idx = lane & 7; idx = idx < t ? idx : t - 1;
        int cv = csr[j + idx];
        int e_w = lane >> 3;
        int se = __shfl(cv, e_w);
        float av = *(const float*)(as1c + (((unsigned)se << 5) + whoff));
        float wall = (e_w < t) ? lrelu_exp(av + adv) : 0.f;
        #pragma unroll
        for (int i = 0; i < 4; i++) {
            int e = 2 * i + g;
            int s = __shfl(cv, e);
            unsigned int u = *(const unsigned int*)(h1c + (((unsigned)s << 7) + coff));
            float w = __shfl(wall, wbase + (i << 4));  // 0 for e >= t
            acc0 = fmaf(w, bf_lo(u), acc0); acc1 = fmaf(w, bf_hi(u), acc1); zl += w;
        }
    }
    float A0 = acc0 + __shfl_xor(acc0, 32);
    float A1 = acc1 + __shfl_xor(acc1, 32);
    float Z  = zl + __shfl_xor(zl, 32);
    if (g == 0) {
        float inv = 1.f / (Z + 1e-16f);
        float v0 = A0 * inv + b1[c0];
        float v1 = A1 * inv + b1[c0 + 1];
        v0 = v0 > 0.f ? v0 : (__expf(v0) - 1.f);
        v1 = v1 > 0.f ? v1 : (__expf(v1) - 1.f);
        *(float2*)&h2[(size_t)n * 64 + c0] = make_float2(v0, v1);
    }
}

// gb[n][40](bf16) = h2[n] @ W2 ; as2/ad2 from fp32 accumulators.
// Block = 64 nodes x 40 cols GEMM tile, K=64. Node-minor staging.
__global__ __launch_bounds__(256) void k_xform2(const float* __restrict__ h2,
                                                const float* __restrict__ W2,
                                                const float* __restrict__ asrc2,
                                                const float* __restrict__ adst2,
                                                ushort_t* __restrict__ gb,
                                                float* __restrict__ as2,
                                                float* __restrict__ ad2, int N) {
    __shared__ float XT[64 * 64];  // h2T[k][node]
    __shared__ float WS[64 * 40];  // WS[k][col]
    int tid = threadIdx.x;
    int n0 = blockIdx.x * 64;
    {   // stage W2: 2560 floats = 640 float4
        const float4* W4 = (const float4*)W2;
        float4* WS4 = (float4*)WS;
        for (int i = tid; i < 640; i += 256) WS4[i] = W4[i];
    }
    {   // stage h2 transposed, node-minor: i = k4*64 + node
        const float4* h4 = (const float4*)h2;
        for (int i = tid; i < 1024; i += 256) {
            int node = i & 63, k4 = i >> 6;
            int gn = n0 + node; if (gn > N - 1) gn = N - 1;
            float4 v = h4[(size_t)gn * 16 + k4];
            int k = k4 * 4;
            XT[(k + 0) * 64 + node] = v.x;
            XT[(k + 1) * 64 + node] = v.y;
            XT[(k + 2) * 64 + node] = v.z;
            XT[(k + 3) * 64 + node] = v.w;
        }
    }
    __syncthreads();
    int ci = tid & 15, ni = tid >> 4;
    int nb = ni * 4, cb = ci * 4;
    float acc[16];
    #pragma unroll
    for (int i = 0; i < 16; i++) acc[i] = 0.f;
    if (ci < 10) {
        #pragma unroll 4
        for (int k = 0; k < 64; k++) {
            float4 xv = *(const float4*)&XT[k * 64 + nb];
            float4 wv = *(const float4*)&WS[k * 40 + cb];
            acc[0]  = fmaf(xv.x, wv.x, acc[0]);  acc[1]  = fmaf(xv.x, wv.y, acc[1]);
            acc[2]  = fmaf(xv.x, wv.z, acc[2]);  acc[3]  = fmaf(xv.x, wv.w, acc[3]);
            acc[4]  = fmaf(xv.y, wv.x, acc[4]);  acc[5]  = fmaf(xv.y, wv.y, acc[5]);
            acc[6]  = fmaf(xv.y, wv.z, acc[6]);  acc[7]  = fmaf(xv.y, wv.w, acc[7]);
            acc[8]  = fmaf(xv.z, wv.x, acc[8]);  acc[9]  = fmaf(xv.z, wv.y, acc[9]);
            acc[10] = fmaf(xv.z, wv.z, acc[10]); acc[11] = fmaf(xv.z, wv.w, acc[11]);
            acc[12] = fmaf(xv.w, wv.x, acc[12]); acc[13] = fmaf(xv.w, wv.y, acc[13]);
            acc[14] = fmaf(xv.w, wv.z, acc[14]); acc[15] = fmaf(xv.w, wv.w, acc[15]);
        }
    }
    #pragma unroll
    for (int i = 0; i < 4; i++) {
        int n = n0 + nb + i;
        if (ci < 10 && n < N) {
            unsigned int p0 = f2bf(acc[i * 4 + 0]) | (f2bf(acc[i * 4 + 1]) << 16);
            unsigned int p1 = f2bf(acc[i * 4 + 2]) | (f2bf(acc[i * 4 + 3]) << 16);
            *(uint2*)&gb[(size_t)n * 40 + cb] = make_uint2(p0, p1);
        }
        float s = 0.f, d = 0.f;
        if (ci < 10) {
            #pragma unroll
            for (int j = 0; j < 4; j++) {
                s = fmaf(acc[i * 4 + j], asrc2[cb + j], s);
                d = fmaf(acc[i * 4 + j], adst2[cb + j], d);
            }
        }
        // reduce over the 16-lane ci group (ci>=10 contribute 0)
        s += __shfl_xor(s, 1); s += __shfl_xor(s, 2);
        s += __shfl_xor(s, 4); s += __shfl_xor(s, 8);
        d += __shfl_xor(d, 1); d += __shfl_xor(d, 2);
        d += __shfl_xor(d, 4); d += __shfl_xor(d, 8);
        if (ci == 0 && n < N) { as2[n] = s; ad2[n] = d; }
    }
}

// Layer-2 aggregation + bias + log_softmax.
// 3 groups x 20 lanes -> THREE 80B rows per gather instruction.
// ONE as2 load + ONE exp per 12-edge chunk (weight lane = lane%12);
// weights distributed via shfl. Lanes 60-63 compute garbage (never read).
__global__ __launch_bounds__(256) void k_agg2(const ushort_t* __restrict__ gb,
                                              const float* __restrict__ as2,
                                              const float* __restrict__ ad2,
                                              const float* __restrict__ b2,
                                              const int* __restrict__ rowptr,
                                              const int* __restrict__ rowEnd,
                                              const int* __restrict__ csr,
                                              float* __restrict__ out, int N) {
    int tid = threadIdx.x, lane = tid & 63;
    int n = blockIdx.x * 4 + (tid >> 6);
    if (n >= N) return;
    int g = lane / 20, p = lane % 20;  // g==3 for lanes 60-63 (results unread)
    int c0 = 2 * p;
    const char* gbc = (const char*)gb;
    unsigned coff = (unsigned)(p << 2);
    int lm12 = lane % 12;
    float add = ad2[n];
    float acc0 = 0.f, acc1 = 0.f, zl = 0.f;
    {   // self loop (group 0 only)
        float e0 = as2[n] + add;
        float w = lrelu_exp(e0);
        if (g == 0) {
            unsigned int u = *(const unsigned int*)(gbc + ((unsigned)n * 80u + coff));
            acc0 = w * bf_lo(u); acc1 = w * bf_hi(u); zl = w;
        }
    }
    int j0 = rowptr[n], j1 = rowEnd[n];
    int j = j0;
    int gi0 = (0 + g) < 12 ? (0 + g) : 11;   // clamp for g==3 lanes
    int gi1 = (3 + g) < 12 ? (3 + g) : 11;
    int gi2 = (6 + g) < 12 ? (6 + g) : 11;
    int gi3 = (9 + g) < 12 ? (9 + g) : 11;
    for (; j + 12 <= j1; j += 12) {
        int cv = csr[j + lm12];          // coalesced, then bpermute
        // one wave-wide weight computation for all 12 edges
        float av = as2[cv];
        float wall = lrelu_exp(av + add);
        int s0 = __shfl(cv, gi0);
        int s1 = __shfl(cv, gi1);
        int s2 = __shfl(cv, gi2);
        int s3 = __shfl(cv, gi3);
        unsigned int u0 = *(const unsigned int*)(gbc + ((unsigned)s0 * 80u + coff));
        unsigned int u1 = *(const unsigned int*)(gbc + ((unsigned)s1 * 80u + coff));
        unsigned int u2 = *(const unsigned int*)(gbc + ((unsigned)s2 * 80u + coff));
        unsigned int u3 = *(const unsigned int*)(gbc + ((unsigned)s3 * 80u + coff));
        float w0 = __shfl(wall, gi0);
        float w1 = __shfl(wall, gi1);
        float w2 = __shfl(wall, gi2);
        float w3 = __shfl(wall, gi3);
        acc0 = fmaf(w0, bf_lo(u0), acc0); acc1 = fmaf(w0, bf_hi(u0), acc1); zl += w0;
        acc0 = fmaf(w1, bf_lo(u1), acc0); acc1 = fmaf(w1, bf_hi(u1), acc1); zl += w1;
        acc0 = fmaf(w2, bf_lo(u2), acc0); acc1 = fmaf(w2, bf_hi(u2), acc1); zl += w2;
        acc0 = fmaf(w3, bf_lo(u3), acc0); acc1 = fmaf(w3, bf_hi(u3), acc1); zl += w3;
    }
    int t = j1 - j;
    if (t > 0) {  // masked 12-wide tail (t in 1..11 -> lane 11's wall is 0)
        int idx = lm12 < t ? lm12 : t - 1;
        int cv = csr[j + idx];
        float av = as2[cv];
        float wall = (lm12 < t) ? lrelu_exp(av + add) : 0.f;
        #pragma unroll
        for (int i = 0; i < 4; i++) {
            int e = 3 * i + g;
            int gi = e < 12 ? e : 11;
            int s = __shfl(cv, gi);
            unsigned int u = *(const unsigned int*)(gbc + ((unsigned)s * 80u + coff));
            float w = __shfl(wall, gi);  // 0 for e >= t
            acc0 = fmaf(w, bf_lo(u), acc0); acc1 = fmaf(w, bf_hi(u), acc1); zl += w;
        }
    }
    // combine the 3 groups (valid at lanes 0..19)
    float A0 = acc0 + __shfl(acc0, (lane + 20) & 63) + __shfl(acc0, (lane + 40) & 63);
    float A1 = acc1 + __shfl(acc1, (lane + 20) & 63) + __shfl(acc1, (lane + 40) & 63);
    float Z  = zl + __shfl(zl, (lane + 20) & 63) + __shfl(zl, (lane + 40) & 63);
    float l0 = 0.f, l1 = 0.f;
    bool active = (lane < 20);
    if (active) {
        float inv = 1.f / (Z + 1e-16f);
        l0 = A0 * inv + b2[c0];
        l1 = A1 * inv + b2[c0 + 1];
    }
    // masked 32-lane butterfly for max and sum-exp over the 40 logits
    float mv = active ? fmaxf(l0, l1) : -INFINITY;
    #pragma unroll
    for (int ofs = 1; ofs < 32; ofs <<= 1) mv = fmaxf(mv, __shfl_xor(mv, ofs));
    float ev = active ? (__expf(l0 - mv) + __expf(l1 - mv)) : 0.f;
    #pragma unroll
    for (int ofs = 1; ofs < 32; ofs <<= 1) ev += __shfl_xor(ev, ofs);
    if (active) {
        float ls = mv + __logf(ev);
        *(float2*)&out[(size_t)n * 40 + c0] = make_float2(l0 - ls, l1 - ls);
    }
}

extern "C" void kernel_launch(void* const* d_in, const int* in_sizes, int n_in,
                              void* d_out, int out_size, void* d_ws, size_t ws_size,
                              hipStream_t stream) {
    const float* x    = (const float*)d_in[0];
    const float* topo = (const float*)d_in[1];
    const int*   ei   = (const int*)d_in[2];
    const float* W1   = (const float*)d_in[3];
    const float* a_s1 = (const float*)d_in[4];
    const float* a_d1 = (const float*)d_in[5];
    const float* b1   = (const float*)d_in[6];
    const float* W2   = (const float*)d_in[7];
    const float* a_s2 = (const float*)d_in[8];
    const float* a_d2 = (const float*)d_in[9];
    const float* b2   = (const float*)d_in[10];
    float* out = (float*)d_out;

    int N = in_sizes[0] / 128;
    int E = in_sizes[2] / 2;
    const int* esrc = ei;
    const int* edst = ei + E;
    int NBUK = (N + 255) / 256;
    size_t cap = (size_t)NBUK * BUK_CAP;

    char* ws = (char*)d_ws;
    size_t off = 0;
    auto alloc = [&](size_t bytes) -> void* {
        void* p = ws + off;
        off = (off + bytes + 255) & ~(size_t)255;
        return p;
    };
    ushort_t* h1b  = (ushort_t*)alloc((size_t)N * 64 * 2);
    float* as1     = (float*)alloc((size_t)N * 8 * 4);
    float* ad1     = (float*)alloc((size_t)N * 8 * 4);
    float* h2      = (float*)alloc((size_t)N * 64 * 4);
    ushort_t* gb   = (ushort_t*)alloc((size_t)N * 40 * 2);
    float* as2     = (float*)alloc((size_t)N * 4);
    float* ad2     = (float*)alloc((size_t)N * 4);
    int*   rowptr  = (int*)alloc((size_t)N * 4);
    int*   rowEnd  = (int*)alloc((size_t)N * 4);
    int*   csr     = (int*)alloc(cap * 4);
    unsigned int* tmp = (unsigned int*)alloc(cap * 4);
    int* gCursor   = (int*)alloc((size_t)NBUK * 4);

    k_initcur<<<(NBUK + 255) / 256, 256, 0, stream>>>(gCursor, NBUK);
    int nbin = (E + BIN_CHUNK - 1) / BIN_CHUNK;
    k_bin<<<nbin, 256, 0, stream>>>(esrc, edst, gCursor, tmp, E, NBUK);
    k_fill2<<<NBUK, 256, 0, stream>>>(tmp, gCursor, rowptr, rowEnd, csr, N);

    int nbg = (N + 63) / 64;  // 64-node GEMM tiles
    int nb4 = (N + 3) / 4;    // 1 node/wave x 4 waves/block
    k_xform1<<<nbg, 256, 0, stream>>>(x, topo, W1, a_s1, a_d1, h1b, as1, ad1, N);
    k_agg1<<<nb4, 256, 0, stream>>>(h1b, as1, ad1, b1, rowptr, rowEnd, csr, h2, N);
    k_xform2<<<nbg, 256, 0, stream>>>(h2, W2, a_s2, a_d2, gb, as2, ad2, N);
    k_agg2<<<nb4, 256, 0, stream>>>(gb, as2, ad2, b2, rowptr, rowEnd, csr, out, N);
}

// Round 15
// 312.869 us; speedup vs baseline: 1.1743x; 1.0331x over previous
//
#include <hip/hip_runtime.h>
#include <math.h>

// ---------------------------------------------------------------------------
// TopoGAT: 2-layer GAT on MI355X.
// R10: fixed-capacity bucket CSR build; padded CSR with rowptr/rowEnd.
// R5:  gather tables h1/g in bf16 (fp8 ruled out: 32x coarser quantization
//      would push absmax ~0.5 >> 0.085 threshold).
// R7/R12: xform = LDS-tiled GEMM, node-minor staging (conflict-free).
// R9/R11/R13: multi-row gathers; masked full-width tails; one wave-wide exp
//      per chunk (weights distributed via shfl).
// R14: CSR build overhauled — k_bin at BIN_CHUNK=4096 (391 blocks, 2x),
//      int4 edge loads with dst STASHED in registers across the barrier
//      (no 6.4MB re-read); k_fill2 at 512 threads + uint4 count pass;
//      gCursor is now a count (hipMemsetAsync 0) — k_initcur launch deleted.
// ---------------------------------------------------------------------------

#define NBUK_MAX 512
#define BIN_CHUNK 4096
#define BUK_CAP 4608

typedef unsigned short ushort_t;

__device__ inline unsigned int f2bf(float f) {  // RNE fp32->bf16
    unsigned int u = __float_as_uint(f);
    u += 0x7FFFu + ((u >> 16) & 1u);
    return u >> 16;
}
__device__ inline float bf_lo(unsigned int u) {
    return __uint_as_float(u << 16);
}
__device__ inline float bf_hi(unsigned int u) {
    return __uint_as_float(u & 0xFFFF0000u);
}
__device__ inline float lrelu_exp(float q) {
    return __expf(q >= 0.f ? q : 0.2f * q);
}

__device__ inline int wave_incl_scan(int v, int lane) {
    #pragma unroll
    for (int ofs = 1; ofs < 64; ofs <<= 1) {
        int t = __shfl_up(v, ofs);
        if (lane >= ofs) v += t;
    }
    return v;
}

// Bin edges into fixed-capacity bucket regions of tmp. One global atomic per
// (block,bucket); packed word = (src<<8) | (dst&255). 16 edges/thread via
// int4 loads; dst stashed in registers across the reservation barrier.
__global__ __launch_bounds__(256) void k_bin(const int* __restrict__ src,
                                             const int* __restrict__ dst,
                                             int* __restrict__ gCursor,
                                             unsigned int* __restrict__ tmp,
                                             int E, int NBUK) {
    __shared__ int lcnt[NBUK_MAX];
    __shared__ int lcur[NBUK_MAX];
    int tid = threadIdx.x;
    int base = blockIdx.x * BIN_CHUNK;
    for (int i = tid; i < NBUK; i += 256) lcnt[i] = 0;
    __syncthreads();
    int d[16];
    #pragma unroll
    for (int q = 0; q < 4; q++) {
        int e = base + q * 1024 + 4 * tid;
        if (e + 3 < E) {
            int4 v = *(const int4*)&dst[e];
            d[4 * q + 0] = v.x; d[4 * q + 1] = v.y;
            d[4 * q + 2] = v.z; d[4 * q + 3] = v.w;
        } else {
            #pragma unroll
            for (int k = 0; k < 4; k++)
                d[4 * q + k] = (e + k < E) ? dst[e + k] : -1;
        }
    }
    #pragma unroll
    for (int k = 0; k < 16; k++)
        if (d[k] >= 0) atomicAdd(&lcnt[d[k] >> 8], 1);
    __syncthreads();
    for (int b = tid; b < NBUK; b += 256) {
        int c = lcnt[b];
        lcur[b] = c ? b * BUK_CAP + atomicAdd(&gCursor[b], c) : 0;
    }
    __syncthreads();
    #pragma unroll
    for (int q = 0; q < 4; q++) {
        int e = base + q * 1024 + 4 * tid;
        int s[4];
        if (e + 3 < E) {
            int4 v = *(const int4*)&src[e];
            s[0] = v.x; s[1] = v.y; s[2] = v.z; s[3] = v.w;
        } else {
            #pragma unroll
            for (int k = 0; k < 4; k++)
                s[k] = (e + k < E) ? src[e + k] : 0;
        }
        #pragma unroll
        for (int k = 0; k < 4; k++) {
            int dd = d[4 * q + k];
            if (dd >= 0) {
                int p = atomicAdd(&lcur[dd >> 8], 1);
                tmp[p] = ((unsigned int)s[k] << 8) | (unsigned int)(dd & 255);
            }
        }
    }
}

// Exact CSR fill within a bucket (padded layout, base = b*BUK_CAP).
// 512 threads; count pass reads tmp as uint4.
__global__ __launch_bounds__(512) void k_fill2(const unsigned int* __restrict__ tmp,
                                               const int* __restrict__ gCursor,
                                               int* __restrict__ rowptr,
                                               int* __restrict__ rowEnd,
                                               int* __restrict__ csr, int N) {
    __shared__ int cnt[256];
    __shared__ int cur[256];
    __shared__ int wsum[4];
    int b = blockIdx.x, tid = threadIdx.x;
    int e0 = b * BUK_CAP;
    int cnt_e = gCursor[b];       // bucket edge count
    int e1 = e0 + cnt_e;
    if (tid < 256) cnt[tid] = 0;
    __syncthreads();
    {   // count pass: uint4 over the bulk (e0 is 16B-aligned: BUK_CAP*4 % 16 == 0)
        int nq = cnt_e >> 2;
        const uint4* t4 = (const uint4*)(tmp + e0);
        for (int q = tid; q < nq; q += 512) {
            uint4 v = t4[q];
            atomicAdd(&cnt[v.x & 255u], 1);
            atomicAdd(&cnt[v.y & 255u], 1);
            atomicAdd(&cnt[v.z & 255u], 1);
            atomicAdd(&cnt[v.w & 255u], 1);
        }
        for (int i = (nq << 2) + tid; i < cnt_e; i += 512)
            atomicAdd(&cnt[tmp[e0 + i] & 255u], 1);
    }
    __syncthreads();
    if (tid < 256) {
        int lane = tid & 63, wv = tid >> 6;
        int v = cnt[tid];
        int incl = wave_incl_scan(v, lane);
        if (lane == 63) wsum[wv] = incl;
        cnt[tid] = incl - v;  // stash exclusive-within-wave
    }
    __syncthreads();
    if (tid < 256) {
        int wv = tid >> 6;
        int woff = 0;
        for (int i = 0; i < wv; i++) woff += wsum[i];
        int excl = woff + cnt[tid];
        int node = b * 256 + tid;
        int start = e0 + excl;
        int deg_end = (tid < 255) ? 0 : 0;  // placeholder (rowEnd set below)
        (void)deg_end;
        cur[tid] = start;
        if (node < N) {
            rowptr[node] = start;
        }
    }
    __syncthreads();
    // rowEnd[node] = next start (cur of tid+1) or e1 for the last
    if (tid < 256) {
        int node = b * 256 + tid;
        if (node < N) rowEnd[node] = (tid < 255) ? cur[tid + 1] : e1;
    }
    __syncthreads();
    for (int i = e0 + tid; i < e1; i += 512) {
        unsigned int t = tmp[i];
        int p = atomicAdd(&cur[t & 255u], 1);
        csr[p] = (int)(t >> 8);
    }
}

// h1b[n][64](bf16) = [x[n]|topo[n]] @ W1 ; as1/ad1 from fp32 accumulators.
// Block = 64 nodes x 64 cols GEMM tile, K=136. W1 + xT staged in LDS,
// node-minor (conflict-free transpose writes).
__global__ __launch_bounds__(256) void k_xform1(const float* __restrict__ x,
                                                const float* __restrict__ topo,
                                                const float* __restrict__ W1,
                                                const float* __restrict__ asrc,
                                                const float* __restrict__ adst,
                                                ushort_t* __restrict__ h1b,
                                                float* __restrict__ as1,
                                                float* __restrict__ ad1, int N) {
    __shared__ float XT[136 * 64];  // XT[k][node]
    __shared__ float WS[136 * 64];  // WS[k][col]
    int tid = threadIdx.x;
    int n0 = blockIdx.x * 64;
    {   // stage W1: 8704 floats = 2176 float4 (once per block)
        const float4* W4 = (const float4*)W1;
        float4* WS4 = (float4*)WS;
        for (int i = tid; i < 2176; i += 256) WS4[i] = W4[i];
    }
    {   // stage x transposed, node-minor: i = k4*64 + node
        const float4* x4 = (const float4*)x;
        for (int i = tid; i < 2048; i += 256) {
            int node = i & 63, k4 = i >> 6;
            int gn = n0 + node; if (gn > N - 1) gn = N - 1;
            float4 v = x4[(size_t)gn * 32 + k4];
            int k = k4 * 4;
            XT[(k + 0) * 64 + node] = v.x;
            XT[(k + 1) * 64 + node] = v.y;
            XT[(k + 2) * 64 + node] = v.z;
            XT[(k + 3) * 64 + node] = v.w;
        }
        // topo rows 128..135: i = j4*64 + node, j4 in {0,1}
        const float4* t4 = (const float4*)topo;
        if (tid < 128) {
            int node = tid & 63, j4 = tid >> 6;
            int gn = n0 + node; if (gn > N - 1) gn = N - 1;
            float4 v = t4[(size_t)gn * 2 + j4];
            int k = 128 + j4 * 4;
            XT[(k + 0) * 64 + node] = v.x;
            XT[(k + 1) * 64 + node] = v.y;
            XT[(k + 2) * 64 + node] = v.z;
            XT[(k + 3) * 64 + node] = v.w;
        }
    }
    __syncthreads();
    int ci = tid & 15, ni = tid >> 4;
    int nb = ni * 4, cb = ci * 4;
    float acc[16];
    #pragma unroll
    for (int i = 0; i < 16; i++) acc[i] = 0.f;
    #pragma unroll 4
    for (int k = 0; k < 136; k++) {
        float4 xv = *(const float4*)&XT[k * 64 + nb];
        float4 wv = *(const float4*)&WS[k * 64 + cb];
        acc[0]  = fmaf(xv.x, wv.x, acc[0]);  acc[1]  = fmaf(xv.x, wv.y, acc[1]);
        acc[2]  = fmaf(xv.x, wv.z, acc[2]);  acc[3]  = fmaf(xv.x, wv.w, acc[3]);
        acc[4]  = fmaf(xv.y, wv.x, acc[4]);  acc[5]  = fmaf(xv.y, wv.y, acc[5]);
        acc[6]  = fmaf(xv.y, wv.z, acc[6]);  acc[7]  = fmaf(xv.y, wv.w, acc[7]);
        acc[8]  = fmaf(xv.z, wv.x, acc[8]);  acc[9]  = fmaf(xv.z, wv.y, acc[9]);
        acc[10] = fmaf(xv.z, wv.z, acc[10]); acc[11] = fmaf(xv.z, wv.w, acc[11]);
        acc[12] = fmaf(xv.w, wv.x, acc[12]); acc[13] = fmaf(xv.w, wv.y, acc[13]);
        acc[14] = fmaf(xv.w, wv.z, acc[14]); acc[15] = fmaf(xv.w, wv.w, acc[15]);
    }
    int head = cb >> 3;  // cols cb..cb+3 lie in one head (cb multiple of 4)
    #pragma unroll
    for (int i = 0; i < 4; i++) {
        int n = n0 + nb + i;
        unsigned int p0 = f2bf(acc[i * 4 + 0]) | (f2bf(acc[i * 4 + 1]) << 16);
        unsigned int p1 = f2bf(acc[i * 4 + 2]) | (f2bf(acc[i * 4 + 3]) << 16);
        if (n < N) *(uint2*)&h1b[(size_t)n * 64 + cb] = make_uint2(p0, p1);
        float s = 0.f, d = 0.f;
        #pragma unroll
        for (int j = 0; j < 4; j++) {
            s = fmaf(acc[i * 4 + j], asrc[cb + j], s);
            d = fmaf(acc[i * 4 + j], adst[cb + j], d);
        }
        s += __shfl_xor(s, 1);  // combine the two half-head threads
        d += __shfl_xor(d, 1);
        if ((ci & 1) == 0 && n < N) {
            as1[n * 8 + head] = s;
            ad1[n * 8 + head] = d;
        }
    }
}

// Per-dst softmax-weighted aggregation, layer 1 (+ implicit self loop).
// 2 groups x 32 lanes -> TWO full 128B rows per gather instruction.
// Weight-lane mapping (edge=lane>>3, head=lane&7): ONE as1 gather + ONE exp
// per 8-edge chunk; weights distributed via shfl.
__global__ __launch_bounds__(256) void k_agg1(const ushort_t* __restrict__ h1b,
                                              const float* __restrict__ as1,
                                              const float* __restrict__ ad1,
                                              const float* __restrict__ b1,
                                              const int* __restrict__ rowptr,
                                              const int* __restrict__ rowEnd,
                                              const int* __restrict__ csr,
                                              float* __restrict__ h2, int N) {
    int tid = threadIdx.x, lane = tid & 63;
    int n = blockIdx.x * 4 + (tid >> 6);
    if (n >= N) return;
    int g = lane >> 5, p = lane & 31;
    int c0 = 2 * p;
    int h = p >> 2;  // head of cols c0, c0+1
    const char* h1c = (const char*)h1b;
    const char* as1c = (const char*)as1;
    unsigned coff = (unsigned)(p << 2);        // c0 * 2 bytes
    unsigned whoff = (unsigned)((lane & 7) << 2);  // weight-lane head * 4 bytes
    int wbase = (g << 3) + h;  // shuffle source base for this compute lane
    float ad_dl = ad1[n * 8 + h];
    float adv = ad1[n * 8 + (lane & 7)];  // weight-lane view
    float acc0 = 0.f, acc1 = 0.f, zl = 0.f;
    {   // self loop (group 0 only)
        float e0 = as1[n * 8 + h] + ad_dl;
        float w = lrelu_exp(e0);
        if (g == 0) {
            unsigned int u = *(const unsigned int*)(h1c + (((unsigned)n << 7) + coff));
            acc0 = w * bf_lo(u); acc1 = w * bf_hi(u); zl = w;
        }
    }
    int j0 = rowptr[n], j1 = rowEnd[n];
    int j = j0;
    for (; j + 8 <= j1; j += 8) {
        int cv = csr[j + (lane & 7)];           // coalesced, then bpermute
        // one wave-wide weight computation: lane = (edge<<3)|head
        int se = __shfl(cv, lane >> 3);
        float av = *(const float*)(as1c + (((unsigned)se << 5) + whoff));
        float wall = lrelu_exp(av + adv);
        int s0 = __shfl(cv, 0 + g);
        int s1 = __shfl(cv, 2 + g);
        int s2 = __shfl(cv, 4 + g);
        int s3 = __shfl(cv, 6 + g);
        unsigned int u0 = *(const unsigned int*)(h1c + (((unsigned)s0 << 7) + coff));
        unsigned int u1 = *(const unsigned int*)(h1c + (((unsigned)s1 << 7) + coff));
        unsigned int u2 = *(const unsigned int*)(h1c + (((unsigned)s2 << 7) + coff));
        unsigned int u3 = *(const unsigned int*)(h1c + (((unsigned)s3 << 7) + coff));
        float w0 = __shfl(wall, wbase);        // edge g,   head h
        float w1 = __shfl(wall, wbase + 16);   // edge 2+g
        float w2 = __shfl(wall, wbase + 32);   // edge 4+g
        float w3 = __shfl(wall, wbase + 48);   // edge 6+g
        acc0 = fmaf(w0, bf_lo(u0), acc0); acc1 = fmaf(w0, bf_hi(u0), acc1); zl += w0;
        acc0 = fmaf(w1, bf_lo(u1), acc0); acc1 = fmaf(w1, bf_hi(u1), acc1); zl += w1;
        acc0 = fmaf(w2, bf_lo(u2), acc0); acc1 = fmaf(w2, bf_hi(u2), acc1); zl += w2;
        acc0 = fmaf(w3, bf_lo(u3), acc0); acc1 = fmaf(w3, bf_hi(u3), acc1); zl += w3;
    }
    int t = j1 - j;
    if (t > 0) {  // masked 8-wide tail: clamped index, zeroed weights
        int idx = lane & 7; idx = idx < t ? idx : t - 1;
        int cv = csr[j + idx];
        int e_w = lane >> 3;
        int se = __shfl(cv, e_w);
        float av = *(const float*)(as1c + (((unsigned)se << 5) + whoff));
        float wall = (e_w < t) ? lrelu_exp(av + adv) : 0.f;
        #pragma unroll
        for (int i = 0; i < 4; i++) {
            int e = 2 * i + g;
            int s = __shfl(cv, e);
            unsigned int u = *(const unsigned int*)(h1c + (((unsigned)s << 7) + coff));
            float w = __shfl(wall, wbase + (i << 4));  // 0 for e >= t
            acc0 = fmaf(w, bf_lo(u), acc0); acc1 = fmaf(w, bf_hi(u), acc1); zl += w;
        }
    }
    float A0 = acc0 + __shfl_xor(acc0, 32);
    float A1 = acc1 + __shfl_xor(acc1, 32);
    float Z  = zl + __shfl_xor(zl, 32);
    if (g == 0) {
        float inv = 1.f / (Z + 1e-16f);
        float v0 = A0 * inv + b1[c0];
        float v1 = A1 * inv + b1[c0 + 1];
        v0 = v0 > 0.f ? v0 : (__expf(v0) - 1.f);
        v1 = v1 > 0.f ? v1 : (__expf(v1) - 1.f);
        *(float2*)&h2[(size_t)n * 64 + c0] = make_float2(v0, v1);
    }
}

// gb[n][40](bf16) = h2[n] @ W2 ; as2/ad2 from fp32 accumulators.
// Block = 64 nodes x 40 cols GEMM tile, K=64. Node-minor staging.
__global__ __launch_bounds__(256) void k_xform2(const float* __restrict__ h2,
                                                const float* __restrict__ W2,
                                                const float* __restrict__ asrc2,
                                                const float* __restrict__ adst2,
                                                ushort_t* __restrict__ gb,
                                                float* __restrict__ as2,
                                                float* __restrict__ ad2, int N) {
    __shared__ float XT[64 * 64];  // h2T[k][node]
    __shared__ float WS[64 * 40];  // WS[k][col]
    int tid = threadIdx.x;
    int n0 = blockIdx.x * 64;
    {   // stage W2: 2560 floats = 640 float4
        const float4* W4 = (const float4*)W2;
        float4* WS4 = (float4*)WS;
        for (int i = tid; i < 640; i += 256) WS4[i] = W4[i];
    }
    {   // stage h2 transposed, node-minor: i = k4*64 + node
        const float4* h4 = (const float4*)h2;
        for (int i = tid; i < 1024; i += 256) {
            int node = i & 63, k4 = i >> 6;
            int gn = n0 + node; if (gn > N - 1) gn = N - 1;
            float4 v = h4[(size_t)gn * 16 + k4];
            int k = k4 * 4;
            XT[(k + 0) * 64 + node] = v.x;
            XT[(k + 1) * 64 + node] = v.y;
            XT[(k + 2) * 64 + node] = v.z;
            XT[(k + 3) * 64 + node] = v.w;
        }
    }
    __syncthreads();
    int ci = tid & 15, ni = tid >> 4;
    int nb = ni * 4, cb = ci * 4;
    float acc[16];
    #pragma unroll
    for (int i = 0; i < 16; i++) acc[i] = 0.f;
    if (ci < 10) {
        #pragma unroll 4
        for (int k = 0; k < 64; k++) {
            float4 xv = *(const float4*)&XT[k * 64 + nb];
            float4 wv = *(const float4*)&WS[k * 40 + cb];
            acc[0]  = fmaf(xv.x, wv.x, acc[0]);  acc[1]  = fmaf(xv.x, wv.y, acc[1]);
            acc[2]  = fmaf(xv.x, wv.z, acc[2]);  acc[3]  = fmaf(xv.x, wv.w, acc[3]);
            acc[4]  = fmaf(xv.y, wv.x, acc[4]);  acc[5]  = fmaf(xv.y, wv.y, acc[5]);
            acc[6]  = fmaf(xv.y, wv.z, acc[6]);  acc[7]  = fmaf(xv.y, wv.w, acc[7]);
            acc[8]  = fmaf(xv.z, wv.x, acc[8]);  acc[9]  = fmaf(xv.z, wv.y, acc[9]);
            acc[10] = fmaf(xv.z, wv.z, acc[10]); acc[11] = fmaf(xv.z, wv.w, acc[11]);
            acc[12] = fmaf(xv.w, wv.x, acc[12]); acc[13] = fmaf(xv.w, wv.y, acc[13]);
            acc[14] = fmaf(xv.w, wv.z, acc[14]); acc[15] = fmaf(xv.w, wv.w, acc[15]);
        }
    }
    #pragma unroll
    for (int i = 0; i < 4; i++) {
        int n = n0 + nb + i;
        if (ci < 10 && n < N) {
            unsigned int p0 = f2bf(acc[i * 4 + 0]) | (f2bf(acc[i * 4 + 1]) << 16);
            unsigned int p1 = f2bf(acc[i * 4 + 2]) | (f2bf(acc[i * 4 + 3]) << 16);
            *(uint2*)&gb[(size_t)n * 40 + cb] = make_uint2(p0, p1);
        }
        float s = 0.f, d = 0.f;
        if (ci < 10) {
            #pragma unroll
            for (int j = 0; j < 4; j++) {
                s = fmaf(acc[i * 4 + j], asrc2[cb + j], s);
                d = fmaf(acc[i * 4 + j], adst2[cb + j], d);
            }
        }
        // reduce over the 16-lane ci group (ci>=10 contribute 0)
        s += __shfl_xor(s, 1); s += __shfl_xor(s, 2);
        s += __shfl_xor(s, 4); s += __shfl_xor(s, 8);
        d += __shfl_xor(d, 1); d += __shfl_xor(d, 2);
        d += __shfl_xor(d, 4); d += __shfl_xor(d, 8);
        if (ci == 0 && n < N) { as2[n] = s; ad2[n] = d; }
    }
}

// Layer-2 aggregation + bias + log_softmax.
// 3 groups x 20 lanes -> THREE 80B rows per gather instruction.
// ONE as2 load + ONE exp per 12-edge chunk; weights via shfl.
__global__ __launch_bounds__(256) void k_agg2(const ushort_t* __restrict__ gb,
                                              const float* __restrict__ as2,
                                              const float* __restrict__ ad2,
                                              const float* __restrict__ b2,
                                              const int* __restrict__ rowptr,
                                              const int* __restrict__ rowEnd,
                                              const int* __restrict__ csr,
                                              float* __restrict__ out, int N) {
    int tid = threadIdx.x, lane = tid & 63;
    int n = blockIdx.x * 4 + (tid >> 6);
    if (n >= N) return;
    int g = lane / 20, p = lane % 20;  // g==3 for lanes 60-63 (results unread)
    int c0 = 2 * p;
    const char* gbc = (const char*)gb;
    unsigned coff = (unsigned)(p << 2);
    int lm12 = lane % 12;
    float add = ad2[n];
    float acc0 = 0.f, acc1 = 0.f, zl = 0.f;
    {   // self loop (group 0 only)
        float e0 = as2[n] + add;
        float w = lrelu_exp(e0);
        if (g == 0) {
            unsigned int u = *(const unsigned int*)(gbc + ((unsigned)n * 80u + coff));
            acc0 = w * bf_lo(u); acc1 = w * bf_hi(u); zl = w;
        }
    }
    int j0 = rowptr[n], j1 = rowEnd[n];
    int j = j0;
    int gi0 = (0 + g) < 12 ? (0 + g) : 11;   // clamp for g==3 lanes
    int gi1 = (3 + g) < 12 ? (3 + g) : 11;
    int gi2 = (6 + g) < 12 ? (6 + g) : 11;
    int gi3 = (9 + g) < 12 ? (9 + g) : 11;
    for (; j + 12 <= j1; j += 12) {
        int cv = csr[j + lm12];          // coalesced, then bpermute
        float av = as2[cv];
        float wall = lrelu_exp(av + add);
        int s0 = __shfl(cv, gi0);
        int s1 = __shfl(cv, gi1);
        int s2 = __shfl(cv, gi2);
        int s3 = __shfl(cv, gi3);
        unsigned int u0 = *(const unsigned int*)(gbc + ((unsigned)s0 * 80u + coff));
        unsigned int u1 = *(const unsigned int*)(gbc + ((unsigned)s1 * 80u + coff));
        unsigned int u2 = *(const unsigned int*)(gbc + ((unsigned)s2 * 80u + coff));
        unsigned int u3 = *(const unsigned int*)(gbc + ((unsigned)s3 * 80u + coff));
        float w0 = __shfl(wall, gi0);
        float w1 = __shfl(wall, gi1);
        float w2 = __shfl(wall, gi2);
        float w3 = __shfl(wall, gi3);
        acc0 = fmaf(w0, bf_lo(u0), acc0); acc1 = fmaf(w0, bf_hi(u0), acc1); zl += w0;
        acc0 = fmaf(w1, bf_lo(u1), acc0); acc1 = fmaf(w1, bf_hi(u1), acc1); zl += w1;
        acc0 = fmaf(w2, bf_lo(u2), acc0); acc1 = fmaf(w2, bf_hi(u2), acc1); zl += w2;
        acc0 = fmaf(w3, bf_lo(u3), acc0); acc1 = fmaf(w3, bf_hi(u3), acc1); zl += w3;
    }
    int t = j1 - j;
    if (t > 0) {  // masked 12-wide tail (t in 1..11 -> lane 11's wall is 0)
        int idx = lm12 < t ? lm12 : t - 1;
        int cv = csr[j + idx];
        float av = as2[cv];
        float wall = (lm12 < t) ? lrelu_exp(av + add) : 0.f;
        #pragma unroll
        for (int i = 0; i < 4; i++) {
            int e = 3 * i + g;
            int gi = e < 12 ? e : 11;
            int s = __shfl(cv, gi);
            unsigned int u = *(const unsigned int*)(gbc + ((unsigned)s * 80u + coff));
            float w = __shfl(wall, gi);  // 0 for e >= t
            acc0 = fmaf(w, bf_lo(u), acc0); acc1 = fmaf(w, bf_hi(u), acc1); zl += w;
        }
    }
    // combine the 3 groups (valid at lanes 0..19)
    float A0 = acc0 + __shfl(acc0, (lane + 20) & 63) + __shfl(acc0, (lane + 40) & 63);
    float A1 = acc1 + __shfl(acc1, (lane + 20) & 63) + __shfl(acc1, (lane + 40) & 63);
    float Z  = zl + __shfl(zl, (lane + 20) & 63) + __shfl(zl, (lane + 40) & 63);
    float l0 = 0.f, l1 = 0.f;
    bool active = (lane < 20);
    if (active) {
        float inv = 1.f / (Z + 1e-16f);
        l0 = A0 * inv + b2[c0];
        l1 = A1 * inv + b2[c0 + 1];
    }
    // masked 32-lane butterfly for max and sum-exp over the 40 logits
    float mv = active ? fmaxf(l0, l1) : -INFINITY;
    #pragma unroll
    for (int ofs = 1; ofs < 32; ofs <<= 1) mv = fmaxf(mv, __shfl_xor(mv, ofs));
    float ev = active ? (__expf(l0 - mv) + __expf(l1 - mv)) : 0.f;
    #pragma unroll
    for (int ofs = 1; ofs < 32; ofs <<= 1) ev += __shfl_xor(ev, ofs);
    if (active) {
        float ls = mv + __logf(ev);
        *(float2*)&out[(size_t)n * 40 + c0] = make_float2(l0 - ls, l1 - ls);
    }
}

extern "C" void kernel_launch(void* const* d_in, const int* in_sizes, int n_in,
                              void* d_out, int out_size, void* d_ws, size_t ws_size,
                              hipStream_t stream) {
    const float* x    = (const float*)d_in[0];
    const float* topo = (const float*)d_in[1];
    const int*   ei   = (const int*)d_in[2];
    const float* W1   = (const float*)d_in[3];
    const float* a_s1 = (const float*)d_in[4];
    const float* a_d1 = (const float*)d_in[5];
    const float* b1   = (const float*)d_in[6];
    const float* W2   = (const float*)d_in[7];
    const float* a_s2 = (const float*)d_in[8];
    const float* a_d2 = (const float*)d_in[9];
    const float* b2   = (const float*)d_in[10];
    float* out = (float*)d_out;

    int N = in_sizes[0] / 128;
    int E = in_sizes[2] / 2;
    const int* esrc = ei;
    const int* edst = ei + E;
    int NBUK = (N + 255) / 256;
    size_t cap = (size_t)NBUK * BUK_CAP;

    char* ws = (char*)d_ws;
    size_t off = 0;
    auto alloc = [&](size_t bytes) -> void* {
        void* p = ws + off;
        off = (off + bytes + 255) & ~(size_t)255;
        return p;
    };
    ushort_t* h1b  = (ushort_t*)alloc((size_t)N * 64 * 2);
    float* as1     = (float*)alloc((size_t)N * 8 * 4);
    float* ad1     = (float*)alloc((size_t)N * 8 * 4);
    float* h2      = (float*)alloc((size_t)N * 64 * 4);
    ushort_t* gb   = (ushort_t*)alloc((size_t)N * 40 * 2);
    float* as2     = (float*)alloc((size_t)N * 4);
    float* ad2     = (float*)alloc((size_t)N * 4);
    int*   rowptr  = (int*)alloc((size_t)N * 4);
    int*   rowEnd  = (int*)alloc((size_t)N * 4);
    int*   csr     = (int*)alloc(cap * 4);
    unsigned int* tmp = (unsigned int*)alloc(cap * 4);
    int* gCursor   = (int*)alloc((size_t)NBUK * 4);

    hipMemsetAsync(gCursor, 0, (size_t)NBUK * 4, stream);  // count-based cursors
    int nbin = (E + BIN_CHUNK - 1) / BIN_CHUNK;
    k_bin<<<nbin, 256, 0, stream>>>(esrc, edst, gCursor, tmp, E, NBUK);
    k_fill2<<<NBUK, 512, 0, stream>>>(tmp, gCursor, rowptr, rowEnd, csr, N);

    int nbg = (N + 63) / 64;  // 64-node GEMM tiles
    int nb4 = (N + 3) / 4;    // 1 node/wave x 4 waves/block
    k_xform1<<<nbg, 256, 0, stream>>>(x, topo, W1, a_s1, a_d1, h1b, as1, ad1, N);
    k_agg1<<<nb4, 256, 0, stream>>>(h1b, as1, ad1, b1, rowptr, rowEnd, csr, h2, N);
    k_xform2<<<nbg, 256, 0, stream>>>(h2, W2, a_s2, a_d2, gb, as2, ad2, N);
    k_agg2<<<nb4, 256, 0, stream>>>(gb, as2, ad2, b2, rowptr, rowEnd, csr, out, N);
}